// Round 5
// baseline (1593.301 us; speedup 1.0000x reference)
//
#include <hip/hip_runtime.h>
#include <hip/hip_bf16.h>
#include <math.h>

#define NTOKEN 60697
#define D_MODEL 512
#define NLAYERS 4
#define D_STATE 16
#define D_CONV 4
#define D_INNER 1024
#define DT_RANK 32
#define B_SZ 4
#define SEQ 2048
#define EPS 1e-5f
#define NROWS (B_SZ * SEQ)   // 8192
#define CHUNK 128
#define NCHUNK (SEQ / CHUNK) // 16

typedef __bf16 bf16_t;
typedef __attribute__((ext_vector_type(8))) __bf16 bfx8;
typedef __attribute__((ext_vector_type(4))) __bf16 bfx4;
typedef __attribute__((ext_vector_type(4))) float f32x4;

// ---------------- utilities ----------------

__device__ __forceinline__ float fast_sigmoid(float x) {
    return 1.0f / (1.0f + __expf(-x));
}
__device__ __forceinline__ float silu(float x) {
    return x * fast_sigmoid(x);
}
__device__ __forceinline__ float softplus_f(float x) {
    return (x > 20.0f) ? x : log1pf(__expf(x));
}

__device__ __forceinline__ void gload_lds16(const void* g, void* l) {
    __builtin_amdgcn_global_load_lds(
        (const __attribute__((address_space(1))) unsigned int*)g,
        (__attribute__((address_space(3))) unsigned int*)l, 16, 0, 0);
}

// DPP fetch within 16-lane row; VALU pipe.
template <int CTRL>
__device__ __forceinline__ float dpp_fetch(float x) {
    int xi = __builtin_bit_cast(int, x);
    int yi = __builtin_amdgcn_update_dpp(0, xi, CTRL, 0xF, 0xF, true);
    return __builtin_bit_cast(float, yi);
}
// butterfly sum over 16-lane group; result in ALL 16 lanes.
__device__ __forceinline__ float dpp_sum16(float p) {
    p += dpp_fetch<0xB1>(p);   // quad_perm xor1
    p += dpp_fetch<0x4E>(p);   // quad_perm xor2
    p += dpp_fetch<0x141>(p);  // row_half_mirror
    p += dpp_fetch<0x140>(p);  // row_mirror
    return p;
}

// block of 256 threads (4 waves). sbuf must be float[4] shared.
__device__ __forceinline__ float blk_reduce_sum(float x, float* sbuf) {
#pragma unroll
    for (int m = 32; m >= 1; m >>= 1) x += __shfl_xor(x, m);
    int wid = threadIdx.x >> 6;
    if ((threadIdx.x & 63) == 0) sbuf[wid] = x;
    __syncthreads();
    float t = sbuf[0] + sbuf[1] + sbuf[2] + sbuf[3];
    __syncthreads();
    return t;
}

// ---------------- fp32 -> bf16 cast (RNE), vector x4 ----------------
__global__ __launch_bounds__(256) void cast_bf16_kernel(
    const float* __restrict__ in, bf16_t* __restrict__ out, size_t n)
{
    size_t stride = (size_t)gridDim.x * 256 * 4;
    for (size_t i = ((size_t)blockIdx.x * 256 + threadIdx.x) * 4; i < n; i += stride) {
        float4 v = *reinterpret_cast<const float4*>(in + i);
        bfx4 o;
        o[0] = (bf16_t)v.x; o[1] = (bf16_t)v.y;
        o[2] = (bf16_t)v.z; o[3] = (bf16_t)v.w;
        *reinterpret_cast<bfx4*>(out + i) = o;
    }
}

// ---------------- Weff[L][n][k] = sum_r dtw[L][n][r] * xw[L][r][k] ----------------
__global__ __launch_bounds__(256) void weff_kernel(
    const float* __restrict__ dtw, const float* __restrict__ xw,
    bf16_t* __restrict__ Weff)
{
    int L = blockIdx.y;
    int idx = blockIdx.x * 256 + threadIdx.x;
    int n = idx >> 10, k = idx & 1023;
    const float* dtwL = dtw + (size_t)L * D_INNER * DT_RANK;
    const float* xwL  = xw  + (size_t)L * (DT_RANK + 2 * D_STATE) * D_INNER;
    float acc = 0.f;
#pragma unroll
    for (int r = 0; r < DT_RANK; r++)
        acc += dtwL[n * DT_RANK + r] * xwL[r * D_INNER + k];
    Weff[(size_t)L * D_INNER * D_INNER + idx] = (bf16_t)acc;
}

// ---------------- embedding + layernorm ----------------

__global__ __launch_bounds__(256) void embed_ln_kernel(
    const int* __restrict__ src, const float* __restrict__ emb,
    const float* __restrict__ w, const float* __restrict__ b,
    float* __restrict__ R)
{
    __shared__ float sbuf[4];
    int row = blockIdx.x;
    int tok = src[row];
    const float* e = emb + (size_t)tok * D_MODEL;
    int c0 = threadIdx.x, c1 = threadIdx.x + 256;
    float v0 = e[c0], v1 = e[c1];
    float mu = blk_reduce_sum(v0 + v1, sbuf) * (1.0f / D_MODEL);
    float d0 = v0 - mu, d1 = v1 - mu;
    float var = blk_reduce_sum(d0 * d0 + d1 * d1, sbuf) * (1.0f / D_MODEL);
    float rs = rsqrtf(var + EPS);
    size_t base = (size_t)row * D_MODEL;
    R[base + c0] = d0 * rs * w[c0] + b[c0];
    R[base + c1] = d1 * rs * w[c1] + b[c1];
}

__global__ __launch_bounds__(256) void add_ln_kernel(
    float* __restrict__ R, const float* __restrict__ Hadd,
    const float* __restrict__ w, const float* __restrict__ b,
    float* __restrict__ out, bf16_t* __restrict__ outb)
{
    __shared__ float sbuf[4];
    size_t base = (size_t)blockIdx.x * D_MODEL;
    int c0 = threadIdx.x, c1 = c0 + 256;
    float v0 = R[base + c0], v1 = R[base + c1];
    if (Hadd) {
        v0 += Hadd[base + c0];
        v1 += Hadd[base + c1];
        R[base + c0] = v0;
        R[base + c1] = v1;
    }
    float mu = blk_reduce_sum(v0 + v1, sbuf) * (1.0f / D_MODEL);
    float d0 = v0 - mu, d1 = v1 - mu;
    float var = blk_reduce_sum(d0 * d0 + d1 * d1, sbuf) * (1.0f / D_MODEL);
    float rs = rsqrtf(var + EPS);
    float o0 = d0 * rs * w[c0] + b[c0];
    float o1 = d1 * rs * w[c1] + b[c1];
    if (out) {
        out[base + c0] = o0;
        out[base + c1] = o1;
    }
    if (outb) {
        outb[base + c0] = (bf16_t)o0;
        outb[base + c1] = (bf16_t)o1;
    }
}

// ---------------- bf16 MFMA GEMM (NT) ----------------
// EPI 0: C[row*ldc+col] = v
// EPI 2: dt-path: v=softplus(v+bias[col]); pack {bf16(v), XCb[row,col]} -> DTXb u32
// EPI 3: split store: col<1024 -> C (Xraw), else Cz (Zbuf)
template <int EPI>
__global__ __launch_bounds__(256) void gemm_bf16_nt(
    const bf16_t* __restrict__ A, const bf16_t* __restrict__ B,
    float* __restrict__ C, int ldc, int K, const float* __restrict__ bias,
    const unsigned short* __restrict__ xcb_u16,
    unsigned short* __restrict__ dtx_u16,
    float* __restrict__ Cz)
{
    __shared__ bf16_t As[128 * 32];
    __shared__ bf16_t Bs[128 * 32];
    int tid = threadIdx.x;
    int lane = tid & 63, wid = tid >> 6;
    int m0 = blockIdx.y * 128, n0 = blockIdx.x * 128;
    int wm = (wid >> 1) * 64, wn = (wid & 1) * 64;
    int c_lo = lane & 15;
    int khalf = lane >> 4;

    f32x4 acc[4][4];
#pragma unroll
    for (int i = 0; i < 4; i++)
#pragma unroll
        for (int j = 0; j < 4; j++)
            acc[i][j] = (f32x4){0.f, 0.f, 0.f, 0.f};

    for (int k0 = 0; k0 < K; k0 += 32) {
#pragma unroll
        for (int i = 0; i < 2; i++) {
            int c = i * 256 + tid;
            int row = c >> 2;
            int cb = (c & 3) * 16;
            int ldsoff = (i * 256 + wid * 64) * 16;
            gload_lds16((const char*)A + ((size_t)(m0 + row) * K + k0) * 2 + cb,
                        (char*)As + ldsoff);
            gload_lds16((const char*)B + ((size_t)(n0 + row) * K + k0) * 2 + cb,
                        (char*)Bs + ldsoff);
        }
        __syncthreads();

        bfx8 af[4], bfr[4];
#pragma unroll
        for (int i = 0; i < 4; i++) {
            af[i]  = *reinterpret_cast<const bfx8*>(As + (wm + i * 16 + c_lo) * 32 + khalf * 8);
            bfr[i] = *reinterpret_cast<const bfx8*>(Bs + (wn + i * 16 + c_lo) * 32 + khalf * 8);
        }
#pragma unroll
        for (int i = 0; i < 4; i++)
#pragma unroll
            for (int j = 0; j < 4; j++)
                acc[i][j] = __builtin_amdgcn_mfma_f32_16x16x32_bf16(af[i], bfr[j], acc[i][j], 0, 0, 0);
        __syncthreads();
    }

#pragma unroll
    for (int i = 0; i < 4; i++) {
#pragma unroll
        for (int j = 0; j < 4; j++) {
            int row0 = m0 + wm + i * 16 + khalf * 4;
            int col = n0 + wn + j * 16 + c_lo;
#pragma unroll
            for (int r = 0; r < 4; r++) {
                int row = row0 + r;
                float v = acc[i][j][r];
                if (EPI == 0) {
                    C[(size_t)row * ldc + col] = v;
                } else if (EPI == 2) {
                    v = softplus_f(v + bias[col]);
                    unsigned int db = (unsigned int)__builtin_bit_cast(unsigned short, (bf16_t)v);
                    unsigned int xb = (unsigned int)xcb_u16[(size_t)row * D_INNER + col];
                    *(unsigned int*)(dtx_u16 + (size_t)row * 2048 + 2 * col) = db | (xb << 16);
                } else if (EPI == 3) {
                    if (col < D_INNER) C[(size_t)row * D_INNER + col] = v;
                    else               Cz[(size_t)row * D_INNER + col - D_INNER] = v;
                }
            }
        }
    }
}

// ---------------- skinny bf16 MFMA GEMM: B/C interleaved out (8192x32) ----------------
__global__ __launch_bounds__(128) void gemm_bc_bf16(
    const bf16_t* __restrict__ A, const bf16_t* __restrict__ Bmat,
    float* __restrict__ BCX, int K)
{
    __shared__ bf16_t As[64 * 32];
    __shared__ bf16_t Bs[32 * 32];
    int tid = threadIdx.x;
    int lane = tid & 63, w = tid >> 6;
    int m0 = blockIdx.x * 64;
    int wr0 = w * 32;
    int c_lo = lane & 15;
    int khalf = lane >> 4;

    f32x4 acc[2][2];
#pragma unroll
    for (int i = 0; i < 2; i++)
#pragma unroll
        for (int j = 0; j < 2; j++)
            acc[i][j] = (f32x4){0.f, 0.f, 0.f, 0.f};

    for (int k0 = 0; k0 < K; k0 += 32) {
        {
            int c = tid;
            gload_lds16((const char*)A + ((size_t)(m0 + (c >> 2)) * K + k0) * 2 + (c & 3) * 16,
                        (char*)As + w * 1024);
        }
        {
            int c = tid + 128;
            gload_lds16((const char*)A + ((size_t)(m0 + (c >> 2)) * K + k0) * 2 + (c & 3) * 16,
                        (char*)As + 2048 + w * 1024);
        }
        {
            int c = tid;
            gload_lds16((const char*)Bmat + ((size_t)(c >> 2) * K + k0) * 2 + (c & 3) * 16,
                        (char*)Bs + w * 1024);
        }
        __syncthreads();

        bfx8 af[2], bfr[2];
#pragma unroll
        for (int i = 0; i < 2; i++)
            af[i] = *reinterpret_cast<const bfx8*>(As + (wr0 + i * 16 + c_lo) * 32 + khalf * 8);
#pragma unroll
        for (int j = 0; j < 2; j++)
            bfr[j] = *reinterpret_cast<const bfx8*>(Bs + (j * 16 + c_lo) * 32 + khalf * 8);
#pragma unroll
        for (int i = 0; i < 2; i++)
#pragma unroll
            for (int j = 0; j < 2; j++)
                acc[i][j] = __builtin_amdgcn_mfma_f32_16x16x32_bf16(af[i], bfr[j], acc[i][j], 0, 0, 0);
        __syncthreads();
    }

    // interleave: BCX[row*32 + 2s] = B_s ; [2s+1] = C_s  (j=0 -> B, j=1 -> C)
#pragma unroll
    for (int i = 0; i < 2; i++)
#pragma unroll
        for (int j = 0; j < 2; j++) {
            int row0 = m0 + wr0 + i * 16 + khalf * 4;
#pragma unroll
            for (int r = 0; r < 4; r++)
                BCX[(size_t)(row0 + r) * 32 + 2 * c_lo + j] = acc[i][j][r];
        }
}

// ---------------- causal depthwise conv + silu -> bf16 ----------------
__global__ __launch_bounds__(256) void conv_silu_kernel(
    const float* __restrict__ Xraw, const float* __restrict__ cw,
    const float* __restrict__ cb, bf16_t* __restrict__ XCb)
{
    size_t gid = (size_t)blockIdx.x * 256 + threadIdx.x;
    int d = (int)(gid & (D_INNER - 1));
    size_t bt = gid >> 10;
    int t = (int)(bt & (SEQ - 1));
    float acc = cb[d];
#pragma unroll
    for (int k = 0; k < D_CONV; k++) {
        int tt = t + k - (D_CONV - 1);
        if (tt >= 0)
            acc += cw[d * D_CONV + k] * Xraw[(bt + (size_t)(k - (D_CONV - 1))) * D_INNER + d];
    }
    XCb[gid] = (bf16_t)silu(acc);
}

// ---------------- scan pass 1: per-chunk local scan ----------------
// grid (B_SZ*64, NCHUNK), 256 threads (16 ch x 16 states).
__global__ __launch_bounds__(256) void scan_p1_kernel(
    const unsigned int* __restrict__ DTXb,   // packed {dt,x} bf16, row = 1024 u32
    const float* __restrict__ BCX,
    const float* __restrict__ A_log,
    float* __restrict__ Y,                   // yloc out
    float* __restrict__ CUM,                 // per-step prefix sum of dt
    float* __restrict__ DcB, float* __restrict__ UcB)
{
    __shared__ __align__(16) char lds[2][6144];  // [0,2048)=dtx, [2048,6144)=bcx
    const int tid = threadIdx.x;
    const int w = tid >> 6, lane = tid & 63;
    const int s = tid & 15, dl = tid >> 4;
    const int b = blockIdx.x >> 6;
    const int d0 = (blockIdx.x & 63) * 16;
    const int c = blockIdx.y;
    const int d = d0 + dl;
    const float Av = -__expf(A_log[d * D_STATE + s]);
    const size_t bbase = (size_t)b * SEQ;
    const int tstart = c * CHUNK;

    auto stage = [&](int slot, int t0) {
        char* base = lds[slot];
        size_t r0 = bbase + tstart + t0;
        if (w < 2) {
            int cdt = w * 64 + lane;  // dtx chunks 0..127 (tile row = 64B = 4 chunks)
            gload_lds16((const char*)DTXb + ((r0 + (cdt >> 2)) * 1024 + d0) * 4 + (cdt & 3) * 16,
                        base + w * 1024);
            int cbc = 128 + w * 64;   // bcx chunks 128..255
            gload_lds16((const char*)BCX + (r0 + ((cbc + lane) >> 3)) * 128 + ((cbc + lane) & 7) * 16,
                        base + 2048 + cbc * 16);
        } else {
            int cbc = (w - 2) * 64;   // bcx chunks 0..127
            gload_lds16((const char*)BCX + (r0 + ((cbc + lane) >> 3)) * 128 + ((cbc + lane) & 7) * 16,
                        base + 2048 + cbc * 16);
        }
    };

    float h = 0.f, cum = 0.f;
    stage(0, 0);
    __syncthreads();
    int cur = 0;
    for (int t0 = 0; t0 < CHUNK; t0 += 32) {
        if (t0 + 32 < CHUNK) stage(cur ^ 1, t0 + 32);
        const char* L = lds[cur];
#pragma unroll
        for (int half = 0; half < 2; half++) {
            float yhold = 0.f, cumhold = 0.f;
#pragma unroll
            for (int k = 0; k < 16; k++) {
                int kk = half * 16 + k;
                unsigned int pk = *(const unsigned int*)(L + kk * 64 + dl * 4);
                float dtv = __builtin_bit_cast(float, pk << 16);
                float xv  = __builtin_bit_cast(float, pk & 0xFFFF0000u);
                float2 bc = *(const float2*)(L + 2048 + kk * 128 + s * 8);
                float e = __expf(dtv * Av);
                h = fmaf(e, h, dtv * xv * bc.x);
                cum += dtv;
                float p = dpp_sum16(h * bc.y);
                if (s == k) { yhold = p; cumhold = cum; }
            }
            int t = tstart + t0 + half * 16 + s;
            size_t row = (bbase + t) * (size_t)D_INNER + d;
            Y[row] = yhold;
            CUM[row] = cumhold;
        }
        __syncthreads();
        cur ^= 1;
    }
    size_t cb64 = ((size_t)c * B_SZ + b) * D_INNER + d;
    UcB[cb64 * 16 + s] = h;
    if (s == 0) DcB[cb64] = cum;
}

// ---------------- scan pass 2: serial chunk-state propagation ----------------
// grid 256 blocks x 256 threads; block = 16 chains x 16 states.
__global__ __launch_bounds__(256) void scan_p2_kernel(
    const float* __restrict__ A_log, const float* __restrict__ DcB,
    const float* __restrict__ UcB, float* __restrict__ HcB)
{
    int tid = threadIdx.x;
    int s = tid & 15, dl = tid >> 4;
    int chain = blockIdx.x * 16 + dl;
    int b = chain >> 10, d = chain & 1023;
    float Av = -__expf(A_log[d * D_STATE + s]);
    float Hv = 0.f;
    for (int c = 0; c < NCHUNK; c++) {
        size_t base = ((size_t)c * B_SZ + b) * D_INNER + d;
        HcB[base * 16 + s] = Hv;   // state at START of chunk c
        Hv = __expf(Av * DcB[base]) * Hv + UcB[base * 16 + s];
    }
}

// ---------------- scan pass 3: correction + combine (fused) ----------------
// grid (B_SZ*64, NCHUNK). Reads x from XCb, writes gated y into XCb in place.
__global__ __launch_bounds__(256) void scan_p3_kernel(
    const float* __restrict__ Y, const float* __restrict__ CUM,
    const float* __restrict__ BCX, const float* __restrict__ HcB,
    const float* __restrict__ A_log, const float* __restrict__ Zbuf,
    const float* __restrict__ Dskip, bf16_t* __restrict__ XCb)
{
    int tid = threadIdx.x;
    int s = tid & 15, dl = tid >> 4;
    int b = blockIdx.x >> 6;
    int d0 = (blockIdx.x & 63) * 16;
    int c = blockIdx.y;
    int d = d0 + dl;
    float Av = -__expf(A_log[d * D_STATE + s]);
    float hc = HcB[(((size_t)c * B_SZ + b) * D_INNER + d) * 16 + s];
    float dsk = Dskip[d];
    size_t bbase = (size_t)b * SEQ;
    int tstart = c * CHUNK;
    for (int t0 = 0; t0 < CHUNK; t0 += 16) {
        float hold = 0.f;
#pragma unroll
        for (int k = 0; k < 16; k++) {
            int t = tstart + t0 + k;
            float cum = CUM[(bbase + t) * (size_t)D_INNER + d];
            float cv  = BCX[(bbase + t) * 32 + 2 * s + 1];
            float p = dpp_sum16(cv * __expf(Av * cum) * hc);
            if (s == k) hold = p;
        }
        int t = tstart + t0 + s;
        size_t row = (bbase + t) * (size_t)D_INNER + d;
        float xv = (float)XCb[row];
        float y = Y[row] + hold + xv * dsk;
        float z = Zbuf[row];
        XCb[row] = (bf16_t)(y * silu(z));
    }
}

// ---------------- launch ----------------

extern "C" void kernel_launch(void* const* d_in, const int* in_sizes, int n_in,
                              void* d_out, int out_size, void* d_ws, size_t ws_size,
                              hipStream_t stream) {
    const int*   src       = (const int*)d_in[0];
    const float* emb_w     = (const float*)d_in[2];
    const float* enc_ln_w  = (const float*)d_in[3];
    const float* enc_ln_b  = (const float*)d_in[4];
    const float* ln_w      = (const float*)d_in[5];
    const float* ln_b      = (const float*)d_in[6];
    const float* in_proj_w = (const float*)d_in[7];
    const float* conv_w    = (const float*)d_in[8];
    const float* conv_b    = (const float*)d_in[9];
    const float* x_proj_w  = (const float*)d_in[10];
    const float* dt_proj_w = (const float*)d_in[11];
    const float* dt_proj_b = (const float*)d_in[12];
    const float* A_log     = (const float*)d_in[13];
    const float* D_skip    = (const float*)d_in[14];
    const float* out_proj_w= (const float*)d_in[15];
    const float* normf_w   = (const float*)d_in[16];
    const float* normf_b   = (const float*)d_in[17];
    float* out = (float*)d_out;

    // fp32 scratch
    float* R    = (float*)d_ws;
    float* H    = R    + (size_t)NROWS * D_MODEL;
    float* Xraw = H    + (size_t)NROWS * D_MODEL;      // conv input; reused as CUM
    float* Zbuf = Xraw + (size_t)NROWS * D_INNER;
    float* Yloc = Zbuf + (size_t)NROWS * D_INNER;
    float* BCX  = Yloc + (size_t)NROWS * D_INNER;      // 8192*32, {B,C} interleaved
    float* DcB  = BCX  + (size_t)NROWS * 32;           // NCHUNK*B_SZ*D_INNER
    float* UcB  = DcB  + (size_t)NCHUNK * B_SZ * D_INNER;
    float* HcB  = UcB  + (size_t)NCHUNK * B_SZ * D_INNER * D_STATE;
    // bf16 / packed scratch
    bf16_t* Hb   = (bf16_t*)(HcB + (size_t)NCHUNK * B_SZ * D_INNER * D_STATE);
    bf16_t* XCb  = Hb  + (size_t)NROWS * D_MODEL;
    unsigned short* DTXb = (unsigned short*)(XCb + (size_t)NROWS * D_INNER); // 8192*2048 u16
    bf16_t* Wib   = (bf16_t*)(DTXb + (size_t)NROWS * 2048);
    bf16_t* Wob   = Wib   + (size_t)NLAYERS * 2 * D_INNER * D_MODEL;
    bf16_t* Weffb = Wob   + (size_t)NLAYERS * D_MODEL * D_INNER;
    bf16_t* xpb   = Weffb + (size_t)NLAYERS * D_INNER * D_INNER;

    // one-time weight prep
    cast_bf16_kernel<<<2048, 256, 0, stream>>>(in_proj_w, Wib, (size_t)NLAYERS * 2 * D_INNER * D_MODEL);
    cast_bf16_kernel<<<2048, 256, 0, stream>>>(out_proj_w, Wob, (size_t)NLAYERS * D_MODEL * D_INNER);
    cast_bf16_kernel<<<256, 256, 0, stream>>>(x_proj_w, xpb, (size_t)NLAYERS * (DT_RANK + 2 * D_STATE) * D_INNER);
    weff_kernel<<<dim3(4096, NLAYERS), 256, 0, stream>>>(dt_proj_w, x_proj_w, Weffb);

    embed_ln_kernel<<<NROWS, 256, 0, stream>>>(src, emb_w, enc_ln_w, enc_ln_b, R);

    for (int L = 0; L < NLAYERS; L++) {
        const float* AlogL = A_log + (size_t)L * D_INNER * D_STATE;

        add_ln_kernel<<<NROWS, 256, 0, stream>>>(
            R, (L == 0) ? nullptr : H, ln_w + L * D_MODEL, ln_b + L * D_MODEL,
            nullptr, Hb);

        // in_proj -> Xraw (x half), Zbuf (z half)
        gemm_bf16_nt<3><<<dim3(16, 64), 256, 0, stream>>>(
            Hb, Wib + (size_t)L * 2 * D_INNER * D_MODEL, Xraw, D_INNER, D_MODEL,
            nullptr, nullptr, nullptr, Zbuf);

        conv_silu_kernel<<<(NROWS * D_INNER) / 256, 256, 0, stream>>>(
            Xraw, conv_w + (size_t)L * D_INNER * D_CONV, conv_b + (size_t)L * D_INNER, XCb);

        // B,C interleaved
        gemm_bc_bf16<<<NROWS / 64, 128, 0, stream>>>(
            XCb, xpb + (size_t)L * 64 * D_INNER + (size_t)DT_RANK * D_INNER, BCX, D_INNER);

        // dt -> DTXb packed {dt, x}
        gemm_bf16_nt<2><<<dim3(8, 64), 256, 0, stream>>>(
            XCb, Weffb + (size_t)L * D_INNER * D_INNER, nullptr, 0, D_INNER,
            dt_proj_b + (size_t)L * D_INNER, (const unsigned short*)XCb, DTXb, nullptr);

        // chunked scan (CUM aliases Xraw — dead after conv)
        scan_p1_kernel<<<dim3(B_SZ * 64, NCHUNK), 256, 0, stream>>>(
            (const unsigned int*)DTXb, BCX, AlogL, Yloc, Xraw, DcB, UcB);
        scan_p2_kernel<<<256, 256, 0, stream>>>(AlogL, DcB, UcB, HcB);
        scan_p3_kernel<<<dim3(B_SZ * 64, NCHUNK), 256, 0, stream>>>(
            Yloc, Xraw, BCX, HcB, AlogL, Zbuf, D_skip + (size_t)L * D_INNER, XCb);

        // out_proj
        gemm_bf16_nt<0><<<dim3(4, 64), 256, 0, stream>>>(
            XCb, Wob + (size_t)L * D_MODEL * D_INNER, H, D_MODEL, D_INNER,
            nullptr, nullptr, nullptr, nullptr);
    }

    add_ln_kernel<<<NROWS, 256, 0, stream>>>(R, H, normf_w, normf_b, out, nullptr);
}

// Round 6
// 1214.299 us; speedup vs baseline: 1.3121x; 1.3121x over previous
//
#include <hip/hip_runtime.h>
#include <hip/hip_bf16.h>
#include <math.h>

#define NTOKEN 60697
#define D_MODEL 512
#define NLAYERS 4
#define D_STATE 16
#define D_CONV 4
#define D_INNER 1024
#define DT_RANK 32
#define B_SZ 4
#define SEQ 2048
#define EPS 1e-5f
#define NROWS (B_SZ * SEQ)   // 8192
#define CHUNK 128
#define NCHUNK (SEQ / CHUNK) // 16

typedef __bf16 bf16_t;
typedef __attribute__((ext_vector_type(8))) __bf16 bfx8;
typedef __attribute__((ext_vector_type(4))) __bf16 bfx4;
typedef __attribute__((ext_vector_type(4))) float f32x4;

// ---------------- utilities ----------------

__device__ __forceinline__ float fast_sigmoid(float x) {
    return 1.0f / (1.0f + __expf(-x));
}
__device__ __forceinline__ float silu(float x) {
    return x * fast_sigmoid(x);
}
__device__ __forceinline__ float softplus_f(float x) {
    return (x > 20.0f) ? x : log1pf(__expf(x));
}

__device__ __forceinline__ void gload_lds16(const void* g, void* l) {
    __builtin_amdgcn_global_load_lds(
        (const __attribute__((address_space(1))) unsigned int*)g,
        (__attribute__((address_space(3))) unsigned int*)l, 16, 0, 0);
}

// DPP fetch within 16-lane row; VALU pipe.
template <int CTRL>
__device__ __forceinline__ float dpp_fetch(float x) {
    int xi = __builtin_bit_cast(int, x);
    int yi = __builtin_amdgcn_update_dpp(0, xi, CTRL, 0xF, 0xF, true);
    return __builtin_bit_cast(float, yi);
}
// butterfly sum over 16-lane group; result in ALL 16 lanes.
__device__ __forceinline__ float dpp_sum16(float p) {
    p += dpp_fetch<0xB1>(p);   // quad_perm xor1
    p += dpp_fetch<0x4E>(p);   // quad_perm xor2
    p += dpp_fetch<0x141>(p);  // row_half_mirror
    p += dpp_fetch<0x140>(p);  // row_mirror
    return p;
}

// block of 256 threads (4 waves). sbuf must be float[4] shared.
__device__ __forceinline__ float blk_reduce_sum(float x, float* sbuf) {
#pragma unroll
    for (int m = 32; m >= 1; m >>= 1) x += __shfl_xor(x, m);
    int wid = threadIdx.x >> 6;
    if ((threadIdx.x & 63) == 0) sbuf[wid] = x;
    __syncthreads();
    float t = sbuf[0] + sbuf[1] + sbuf[2] + sbuf[3];
    __syncthreads();
    return t;
}

// ---------------- fp32 -> bf16 cast (RNE), vector x4 ----------------
__global__ __launch_bounds__(256) void cast_bf16_kernel(
    const float* __restrict__ in, bf16_t* __restrict__ out, size_t n)
{
    size_t stride = (size_t)gridDim.x * 256 * 4;
    for (size_t i = ((size_t)blockIdx.x * 256 + threadIdx.x) * 4; i < n; i += stride) {
        float4 v = *reinterpret_cast<const float4*>(in + i);
        bfx4 o;
        o[0] = (bf16_t)v.x; o[1] = (bf16_t)v.y;
        o[2] = (bf16_t)v.z; o[3] = (bf16_t)v.w;
        *reinterpret_cast<bfx4*>(out + i) = o;
    }
}

// ---------------- Weff[L][n][k] = sum_r dtw[L][n][r] * xw[L][r][k] ----------------
__global__ __launch_bounds__(256) void weff_kernel(
    const float* __restrict__ dtw, const float* __restrict__ xw,
    bf16_t* __restrict__ Weff)
{
    int L = blockIdx.y;
    int idx = blockIdx.x * 256 + threadIdx.x;
    int n = idx >> 10, k = idx & 1023;
    const float* dtwL = dtw + (size_t)L * D_INNER * DT_RANK;
    const float* xwL  = xw  + (size_t)L * (DT_RANK + 2 * D_STATE) * D_INNER;
    float acc = 0.f;
#pragma unroll
    for (int r = 0; r < DT_RANK; r++)
        acc += dtwL[n * DT_RANK + r] * xwL[r * D_INNER + k];
    Weff[(size_t)L * D_INNER * D_INNER + idx] = (bf16_t)acc;
}

// ---------------- embedding + layernorm ----------------

__global__ __launch_bounds__(256) void embed_ln_kernel(
    const int* __restrict__ src, const float* __restrict__ emb,
    const float* __restrict__ w, const float* __restrict__ b,
    float* __restrict__ R)
{
    __shared__ float sbuf[4];
    int row = blockIdx.x;
    int tok = src[row];
    const float* e = emb + (size_t)tok * D_MODEL;
    int c0 = threadIdx.x, c1 = threadIdx.x + 256;
    float v0 = e[c0], v1 = e[c1];
    float mu = blk_reduce_sum(v0 + v1, sbuf) * (1.0f / D_MODEL);
    float d0 = v0 - mu, d1 = v1 - mu;
    float var = blk_reduce_sum(d0 * d0 + d1 * d1, sbuf) * (1.0f / D_MODEL);
    float rs = rsqrtf(var + EPS);
    size_t base = (size_t)row * D_MODEL;
    R[base + c0] = d0 * rs * w[c0] + b[c0];
    R[base + c1] = d1 * rs * w[c1] + b[c1];
}

__global__ __launch_bounds__(256) void add_ln_kernel(
    float* __restrict__ R, const float* __restrict__ Hadd,
    const float* __restrict__ w, const float* __restrict__ b,
    float* __restrict__ out, bf16_t* __restrict__ outb)
{
    __shared__ float sbuf[4];
    size_t base = (size_t)blockIdx.x * D_MODEL;
    int c0 = threadIdx.x, c1 = c0 + 256;
    float v0 = R[base + c0], v1 = R[base + c1];
    if (Hadd) {
        v0 += Hadd[base + c0];
        v1 += Hadd[base + c1];
        R[base + c0] = v0;
        R[base + c1] = v1;
    }
    float mu = blk_reduce_sum(v0 + v1, sbuf) * (1.0f / D_MODEL);
    float d0 = v0 - mu, d1 = v1 - mu;
    float var = blk_reduce_sum(d0 * d0 + d1 * d1, sbuf) * (1.0f / D_MODEL);
    float rs = rsqrtf(var + EPS);
    float o0 = d0 * rs * w[c0] + b[c0];
    float o1 = d1 * rs * w[c1] + b[c1];
    if (out) {
        out[base + c0] = o0;
        out[base + c1] = o1;
    }
    if (outb) {
        outb[base + c0] = (bf16_t)o0;
        outb[base + c1] = (bf16_t)o1;
    }
}

// ---------------- bf16 MFMA GEMM (NT) ----------------
// EPI 0: C[row*ldc+col] = v
// EPI 2: dt-path: v=softplus(v+bias[col]); pack {bf16(v), XCb[row,col]} -> DTXb u32
// EPI 3: split store: col<1024 -> C (Xraw), else Cz (Zbuf)
template <int EPI>
__global__ __launch_bounds__(256) void gemm_bf16_nt(
    const bf16_t* __restrict__ A, const bf16_t* __restrict__ B,
    float* __restrict__ C, int ldc, int K, const float* __restrict__ bias,
    const unsigned short* __restrict__ xcb_u16,
    unsigned short* __restrict__ dtx_u16,
    float* __restrict__ Cz)
{
    __shared__ bf16_t As[128 * 32];
    __shared__ bf16_t Bs[128 * 32];
    int tid = threadIdx.x;
    int lane = tid & 63, wid = tid >> 6;
    int m0 = blockIdx.y * 128, n0 = blockIdx.x * 128;
    int wm = (wid >> 1) * 64, wn = (wid & 1) * 64;
    int c_lo = lane & 15;
    int khalf = lane >> 4;

    f32x4 acc[4][4];
#pragma unroll
    for (int i = 0; i < 4; i++)
#pragma unroll
        for (int j = 0; j < 4; j++)
            acc[i][j] = (f32x4){0.f, 0.f, 0.f, 0.f};

    for (int k0 = 0; k0 < K; k0 += 32) {
#pragma unroll
        for (int i = 0; i < 2; i++) {
            int c = i * 256 + tid;
            int row = c >> 2;
            int cb = (c & 3) * 16;
            int ldsoff = (i * 256 + wid * 64) * 16;
            gload_lds16((const char*)A + ((size_t)(m0 + row) * K + k0) * 2 + cb,
                        (char*)As + ldsoff);
            gload_lds16((const char*)B + ((size_t)(n0 + row) * K + k0) * 2 + cb,
                        (char*)Bs + ldsoff);
        }
        __syncthreads();

        bfx8 af[4], bfr[4];
#pragma unroll
        for (int i = 0; i < 4; i++) {
            af[i]  = *reinterpret_cast<const bfx8*>(As + (wm + i * 16 + c_lo) * 32 + khalf * 8);
            bfr[i] = *reinterpret_cast<const bfx8*>(Bs + (wn + i * 16 + c_lo) * 32 + khalf * 8);
        }
#pragma unroll
        for (int i = 0; i < 4; i++)
#pragma unroll
            for (int j = 0; j < 4; j++)
                acc[i][j] = __builtin_amdgcn_mfma_f32_16x16x32_bf16(af[i], bfr[j], acc[i][j], 0, 0, 0);
        __syncthreads();
    }

#pragma unroll
    for (int i = 0; i < 4; i++) {
#pragma unroll
        for (int j = 0; j < 4; j++) {
            int row0 = m0 + wm + i * 16 + khalf * 4;
            int col = n0 + wn + j * 16 + c_lo;
#pragma unroll
            for (int r = 0; r < 4; r++) {
                int row = row0 + r;
                float v = acc[i][j][r];
                if (EPI == 0) {
                    C[(size_t)row * ldc + col] = v;
                } else if (EPI == 2) {
                    v = softplus_f(v + bias[col]);
                    unsigned int db = (unsigned int)__builtin_bit_cast(unsigned short, (bf16_t)v);
                    unsigned int xb = (unsigned int)xcb_u16[(size_t)row * D_INNER + col];
                    *(unsigned int*)(dtx_u16 + (size_t)row * 2048 + 2 * col) = db | (xb << 16);
                } else if (EPI == 3) {
                    if (col < D_INNER) C[(size_t)row * D_INNER + col] = v;
                    else               Cz[(size_t)row * D_INNER + col - D_INNER] = v;
                }
            }
        }
    }
}

// ---------------- skinny bf16 MFMA GEMM: B/C interleaved out (8192x32) ----------------
__global__ __launch_bounds__(128) void gemm_bc_bf16(
    const bf16_t* __restrict__ A, const bf16_t* __restrict__ Bmat,
    float* __restrict__ BCX, int K)
{
    __shared__ bf16_t As[64 * 32];
    __shared__ bf16_t Bs[32 * 32];
    int tid = threadIdx.x;
    int lane = tid & 63, w = tid >> 6;
    int m0 = blockIdx.x * 64;
    int wr0 = w * 32;
    int c_lo = lane & 15;
    int khalf = lane >> 4;

    f32x4 acc[2][2];
#pragma unroll
    for (int i = 0; i < 2; i++)
#pragma unroll
        for (int j = 0; j < 2; j++)
            acc[i][j] = (f32x4){0.f, 0.f, 0.f, 0.f};

    for (int k0 = 0; k0 < K; k0 += 32) {
        {
            int c = tid;
            gload_lds16((const char*)A + ((size_t)(m0 + (c >> 2)) * K + k0) * 2 + (c & 3) * 16,
                        (char*)As + w * 1024);
        }
        {
            int c = tid + 128;
            gload_lds16((const char*)A + ((size_t)(m0 + (c >> 2)) * K + k0) * 2 + (c & 3) * 16,
                        (char*)As + 2048 + w * 1024);
        }
        {
            int c = tid;
            gload_lds16((const char*)Bmat + ((size_t)(c >> 2) * K + k0) * 2 + (c & 3) * 16,
                        (char*)Bs + w * 1024);
        }
        __syncthreads();

        bfx8 af[2], bfr[2];
#pragma unroll
        for (int i = 0; i < 2; i++)
            af[i] = *reinterpret_cast<const bfx8*>(As + (wr0 + i * 16 + c_lo) * 32 + khalf * 8);
#pragma unroll
        for (int j = 0; j < 2; j++)
            bfr[j] = *reinterpret_cast<const bfx8*>(Bs + (j * 16 + c_lo) * 32 + khalf * 8);
#pragma unroll
        for (int i = 0; i < 2; i++)
#pragma unroll
            for (int j = 0; j < 2; j++)
                acc[i][j] = __builtin_amdgcn_mfma_f32_16x16x32_bf16(af[i], bfr[j], acc[i][j], 0, 0, 0);
        __syncthreads();
    }

    // interleave: BCX[row*32 + 2s] = B_s ; [2s+1] = C_s
#pragma unroll
    for (int i = 0; i < 2; i++)
#pragma unroll
        for (int j = 0; j < 2; j++) {
            int row0 = m0 + wr0 + i * 16 + khalf * 4;
#pragma unroll
            for (int r = 0; r < 4; r++)
                BCX[(size_t)(row0 + r) * 32 + 2 * c_lo + j] = acc[i][j][r];
        }
}

// ---------------- causal depthwise conv + silu -> bf16 ----------------
__global__ __launch_bounds__(256) void conv_silu_kernel(
    const float* __restrict__ Xraw, const float* __restrict__ cw,
    const float* __restrict__ cb, bf16_t* __restrict__ XCb)
{
    size_t gid = (size_t)blockIdx.x * 256 + threadIdx.x;
    int d = (int)(gid & (D_INNER - 1));
    size_t bt = gid >> 10;
    int t = (int)(bt & (SEQ - 1));
    float acc = cb[d];
#pragma unroll
    for (int k = 0; k < D_CONV; k++) {
        int tt = t + k - (D_CONV - 1);
        if (tt >= 0)
            acc += cw[d * D_CONV + k] * Xraw[(bt + (size_t)(k - (D_CONV - 1))) * D_INNER + d];
    }
    XCb[gid] = (bf16_t)silu(acc);
}

// ---------------- staging helper for scan passes ----------------
// LDS slot layout (bytes): [0,2048) dtx (32 steps x 16ch u32), [2048,6144) bcx
// (32 steps x 32 f32). 256 threads; w = tid>>6, lane = tid&63.
__device__ __forceinline__ void scan_stage(
    char* base, const unsigned int* __restrict__ DTXb,
    const float* __restrict__ BCX, size_t r0, int d0, int w, int lane)
{
    if (w < 2) {
        int cdt = w * 64 + lane;  // dtx chunks 0..127
        gload_lds16((const char*)DTXb + ((r0 + (cdt >> 2)) * 1024 + d0) * 4 + (cdt & 3) * 16,
                    base + w * 1024);
        int cbc = 128 + w * 64;   // bcx chunks 128..255
        gload_lds16((const char*)BCX + (r0 + ((cbc + lane) >> 3)) * 128 + ((cbc + lane) & 7) * 16,
                    base + 2048 + cbc * 16);
    } else {
        int cbc = (w - 2) * 64;   // bcx chunks 0..127
        gload_lds16((const char*)BCX + (r0 + ((cbc + lane) >> 3)) * 128 + ((cbc + lane) & 7) * 16,
                    base + 2048 + cbc * 16);
    }
}

// ---------------- scan pass A: chunk summaries only ----------------
// grid (B_SZ*64, NCHUNK), 256 threads (16 ch x 16 states). No per-step output.
__global__ __launch_bounds__(256) void scan_pA_kernel(
    const unsigned int* __restrict__ DTXb, const float* __restrict__ BCX,
    const float* __restrict__ A_log,
    float* __restrict__ DcB, float* __restrict__ UcB)
{
    __shared__ __align__(16) char lds[2][6144];
    const int tid = threadIdx.x;
    const int w = tid >> 6, lane = tid & 63;
    const int s = tid & 15, dl = tid >> 4;
    const int b = blockIdx.x >> 6;
    const int d0 = (blockIdx.x & 63) * 16;
    const int c = blockIdx.y;
    const int d = d0 + dl;
    const float Av = -__expf(A_log[d * D_STATE + s]);
    const size_t bbase = (size_t)b * SEQ;
    const int tstart = c * CHUNK;

    float h = 0.f, cum = 0.f;
    scan_stage(lds[0], DTXb, BCX, bbase + tstart, d0, w, lane);
    __syncthreads();
    int cur = 0;
    for (int t0 = 0; t0 < CHUNK; t0 += 32) {
        if (t0 + 32 < CHUNK)
            scan_stage(lds[cur ^ 1], DTXb, BCX, bbase + tstart + t0 + 32, d0, w, lane);
        const char* L = lds[cur];
#pragma unroll
        for (int kk = 0; kk < 32; kk++) {
            unsigned int pk = *(const unsigned int*)(L + kk * 64 + dl * 4);
            float dtv = __builtin_bit_cast(float, pk << 16);
            float xv  = __builtin_bit_cast(float, pk & 0xFFFF0000u);
            float bv  = *(const float*)(L + 2048 + kk * 128 + s * 8);
            float e = __expf(dtv * Av);
            h = fmaf(e, h, dtv * xv * bv);
            cum += dtv;
        }
        __syncthreads();
        cur ^= 1;
    }
    size_t cb64 = ((size_t)c * B_SZ + b) * D_INNER + d;
    UcB[cb64 * 16 + s] = h;
    if (s == 0) DcB[cb64] = cum;
}

// ---------------- scan pass 2: serial chunk-state propagation ----------------
__global__ __launch_bounds__(256) void scan_p2_kernel(
    const float* __restrict__ A_log, const float* __restrict__ DcB,
    const float* __restrict__ UcB, float* __restrict__ HcB)
{
    int tid = threadIdx.x;
    int s = tid & 15, dl = tid >> 4;
    int chain = blockIdx.x * 16 + dl;
    int b = chain >> 10, d = chain & 1023;
    float Av = -__expf(A_log[d * D_STATE + s]);
    float Hv = 0.f;
    for (int c = 0; c < NCHUNK; c++) {
        size_t base = ((size_t)c * B_SZ + b) * D_INNER + d;
        HcB[base * 16 + s] = Hv;   // state at START of chunk c
        Hv = __expf(Av * DcB[base]) * Hv + UcB[base * 16 + s];
    }
}

// ---------------- scan pass B: recompute local scan from chunk-start state,
// produce y, fused combine, coalesced via LDS transpose tile ----------------
// grid (B_SZ*64, NCHUNK), 256 threads.
__global__ __launch_bounds__(256) void scan_pB_kernel(
    const unsigned int* __restrict__ DTXb, const float* __restrict__ BCX,
    const float* __restrict__ HcB, const float* __restrict__ A_log,
    const float* __restrict__ Zbuf, const float* __restrict__ Dskip,
    bf16_t* __restrict__ XCb)
{
    __shared__ __align__(16) char lds[2][6144];
    __shared__ float ytile[32][17];
    const int tid = threadIdx.x;
    const int w = tid >> 6, lane = tid & 63;
    const int s = tid & 15, dl = tid >> 4;
    const int b = blockIdx.x >> 6;
    const int d0 = (blockIdx.x & 63) * 16;
    const int c = blockIdx.y;
    const int d = d0 + dl;
    const float Av = -__expf(A_log[d * D_STATE + s]);
    const size_t bbase = (size_t)b * SEQ;
    const int tstart = c * CHUNK;

    float h = HcB[(((size_t)c * B_SZ + b) * D_INNER + d) * 16 + s];

    // combine-phase per-thread constants: idx = tid*2 over [32 t][16 d] tile
    const int tl  = tid >> 3;            // 0..31
    const int dlo = (tid * 2) & 15;      // even
    const float dsk0 = Dskip[d0 + dlo];
    const float dsk1 = Dskip[d0 + dlo + 1];

    scan_stage(lds[0], DTXb, BCX, bbase + tstart, d0, w, lane);
    __syncthreads();
    int cur = 0;
    for (int t0 = 0; t0 < CHUNK; t0 += 32) {
        if (t0 + 32 < CHUNK)
            scan_stage(lds[cur ^ 1], DTXb, BCX, bbase + tstart + t0 + 32, d0, w, lane);
        const char* L = lds[cur];
#pragma unroll
        for (int half = 0; half < 2; half++) {
            float yhold = 0.f;
#pragma unroll
            for (int k = 0; k < 16; k++) {
                int kk = half * 16 + k;
                unsigned int pk = *(const unsigned int*)(L + kk * 64 + dl * 4);
                float dtv = __builtin_bit_cast(float, pk << 16);
                float xv  = __builtin_bit_cast(float, pk & 0xFFFF0000u);
                float2 bc = *(const float2*)(L + 2048 + kk * 128 + s * 8);
                float e = __expf(dtv * Av);
                h = fmaf(e, h, dtv * xv * bc.x);
                float p = dpp_sum16(h * bc.y);
                if (s == k) yhold = p;
            }
            ytile[half * 16 + s][dl] = yhold;  // lane (dl,s): y(t=t0+half*16+s, d)
        }
        __syncthreads();   // ytile ready; staged tile for next group ready

        // combine + coalesced store: thread handles (t = t0+tl, d = d0+dlo, +1)
        {
            int t = tstart + t0 + tl;
            size_t row = (bbase + t) * (size_t)D_INNER + d0 + dlo;
            float y0 = ytile[tl][dlo];
            float y1 = ytile[tl][dlo + 1];
            unsigned int xw = *(const unsigned int*)(XCb + row);
            float x0 = __builtin_bit_cast(float, xw << 16);
            float x1 = __builtin_bit_cast(float, xw & 0xFFFF0000u);
            float2 z2 = *(const float2*)(Zbuf + row);
            float g0 = (y0 + x0 * dsk0) * silu(z2.x);
            float g1 = (y1 + x1 * dsk1) * silu(z2.y);
            unsigned int o = (unsigned int)__builtin_bit_cast(unsigned short, (bf16_t)g0)
                           | ((unsigned int)__builtin_bit_cast(unsigned short, (bf16_t)g1) << 16);
            *(unsigned int*)(XCb + row) = o;
        }
        __syncthreads();   // ytile reads done before next group's writes
        cur ^= 1;
    }
}

// ---------------- launch ----------------

extern "C" void kernel_launch(void* const* d_in, const int* in_sizes, int n_in,
                              void* d_out, int out_size, void* d_ws, size_t ws_size,
                              hipStream_t stream) {
    const int*   src       = (const int*)d_in[0];
    const float* emb_w     = (const float*)d_in[2];
    const float* enc_ln_w  = (const float*)d_in[3];
    const float* enc_ln_b  = (const float*)d_in[4];
    const float* ln_w      = (const float*)d_in[5];
    const float* ln_b      = (const float*)d_in[6];
    const float* in_proj_w = (const float*)d_in[7];
    const float* conv_w    = (const float*)d_in[8];
    const float* conv_b    = (const float*)d_in[9];
    const float* x_proj_w  = (const float*)d_in[10];
    const float* dt_proj_w = (const float*)d_in[11];
    const float* dt_proj_b = (const float*)d_in[12];
    const float* A_log     = (const float*)d_in[13];
    const float* D_skip    = (const float*)d_in[14];
    const float* out_proj_w= (const float*)d_in[15];
    const float* normf_w   = (const float*)d_in[16];
    const float* normf_b   = (const float*)d_in[17];
    float* out = (float*)d_out;

    // fp32 scratch
    float* R    = (float*)d_ws;
    float* H    = R    + (size_t)NROWS * D_MODEL;
    float* Xraw = H    + (size_t)NROWS * D_MODEL;
    float* Zbuf = Xraw + (size_t)NROWS * D_INNER;
    float* BCX  = Zbuf + (size_t)NROWS * D_INNER;      // 8192*32, {B,C} interleaved
    float* DcB  = BCX  + (size_t)NROWS * 32;           // NCHUNK*B_SZ*D_INNER
    float* UcB  = DcB  + (size_t)NCHUNK * B_SZ * D_INNER;
    float* HcB  = UcB  + (size_t)NCHUNK * B_SZ * D_INNER * D_STATE;
    // bf16 / packed scratch
    bf16_t* Hb   = (bf16_t*)(HcB + (size_t)NCHUNK * B_SZ * D_INNER * D_STATE);
    bf16_t* XCb  = Hb  + (size_t)NROWS * D_MODEL;
    unsigned short* DTXb = (unsigned short*)(XCb + (size_t)NROWS * D_INNER); // 8192*2048 u16
    bf16_t* Wib   = (bf16_t*)(DTXb + (size_t)NROWS * 2048);
    bf16_t* Wob   = Wib   + (size_t)NLAYERS * 2 * D_INNER * D_MODEL;
    bf16_t* Weffb = Wob   + (size_t)NLAYERS * D_MODEL * D_INNER;
    bf16_t* xpb   = Weffb + (size_t)NLAYERS * D_INNER * D_INNER;

    // one-time weight prep
    cast_bf16_kernel<<<2048, 256, 0, stream>>>(in_proj_w, Wib, (size_t)NLAYERS * 2 * D_INNER * D_MODEL);
    cast_bf16_kernel<<<2048, 256, 0, stream>>>(out_proj_w, Wob, (size_t)NLAYERS * D_MODEL * D_INNER);
    cast_bf16_kernel<<<256, 256, 0, stream>>>(x_proj_w, xpb, (size_t)NLAYERS * (DT_RANK + 2 * D_STATE) * D_INNER);
    weff_kernel<<<dim3(4096, NLAYERS), 256, 0, stream>>>(dt_proj_w, x_proj_w, Weffb);

    embed_ln_kernel<<<NROWS, 256, 0, stream>>>(src, emb_w, enc_ln_w, enc_ln_b, R);

    for (int L = 0; L < NLAYERS; L++) {
        const float* AlogL = A_log + (size_t)L * D_INNER * D_STATE;

        add_ln_kernel<<<NROWS, 256, 0, stream>>>(
            R, (L == 0) ? nullptr : H, ln_w + L * D_MODEL, ln_b + L * D_MODEL,
            nullptr, Hb);

        // in_proj -> Xraw (x half), Zbuf (z half)
        gemm_bf16_nt<3><<<dim3(16, 64), 256, 0, stream>>>(
            Hb, Wib + (size_t)L * 2 * D_INNER * D_MODEL, Xraw, D_INNER, D_MODEL,
            nullptr, nullptr, nullptr, Zbuf);

        conv_silu_kernel<<<(NROWS * D_INNER) / 256, 256, 0, stream>>>(
            Xraw, conv_w + (size_t)L * D_INNER * D_CONV, conv_b + (size_t)L * D_INNER, XCb);

        // B,C interleaved
        gemm_bc_bf16<<<NROWS / 64, 128, 0, stream>>>(
            XCb, xpb + (size_t)L * 64 * D_INNER + (size_t)DT_RANK * D_INNER, BCX, D_INNER);

        // dt -> DTXb packed {dt, x}
        gemm_bf16_nt<2><<<dim3(8, 64), 256, 0, stream>>>(
            XCb, Weffb + (size_t)L * D_INNER * D_INNER, nullptr, 0, D_INNER,
            dt_proj_b + (size_t)L * D_INNER, (const unsigned short*)XCb, DTXb, nullptr);

        // chunked scan: summaries -> propagate -> recompute+combine
        scan_pA_kernel<<<dim3(B_SZ * 64, NCHUNK), 256, 0, stream>>>(
            (const unsigned int*)DTXb, BCX, AlogL, DcB, UcB);
        scan_p2_kernel<<<256, 256, 0, stream>>>(AlogL, DcB, UcB, HcB);
        scan_pB_kernel<<<dim3(B_SZ * 64, NCHUNK), 256, 0, stream>>>(
            (const unsigned int*)DTXb, BCX, HcB, AlogL, Zbuf,
            D_skip + (size_t)L * D_INNER, XCb);

        // out_proj
        gemm_bf16_nt<0><<<dim3(4, 64), 256, 0, stream>>>(
            XCb, Wob + (size_t)L * D_MODEL * D_INNER, H, D_MODEL, D_INNER,
            nullptr, nullptr, nullptr, nullptr);
    }

    add_ln_kernel<<<NROWS, 256, 0, stream>>>(R, H, normf_w, normf_b, out, nullptr);
}

// Round 7
// 1091.309 us; speedup vs baseline: 1.4600x; 1.1127x over previous
//
#include <hip/hip_runtime.h>
#include <hip/hip_bf16.h>
#include <math.h>

#define NTOKEN 60697
#define D_MODEL 512
#define NLAYERS 4
#define D_STATE 16
#define D_CONV 4
#define D_INNER 1024
#define DT_RANK 32
#define B_SZ 4
#define SEQ 2048
#define EPS 1e-5f
#define NROWS (B_SZ * SEQ)   // 8192
#define CHUNK 128
#define NCHUNK (SEQ / CHUNK) // 16

typedef __bf16 bf16_t;
typedef __attribute__((ext_vector_type(8))) __bf16 bfx8;
typedef __attribute__((ext_vector_type(4))) __bf16 bfx4;
typedef __attribute__((ext_vector_type(4))) float f32x4;

// ---------------- utilities ----------------

__device__ __forceinline__ float fast_sigmoid(float x) {
    return 1.0f / (1.0f + __expf(-x));
}
__device__ __forceinline__ float silu(float x) {
    return x * fast_sigmoid(x);
}
__device__ __forceinline__ float softplus_f(float x) {
    return (x > 20.0f) ? x : log1pf(__expf(x));
}

__device__ __forceinline__ void gload_lds16(const void* g, void* l) {
    __builtin_amdgcn_global_load_lds(
        (const __attribute__((address_space(1))) unsigned int*)g,
        (__attribute__((address_space(3))) unsigned int*)l, 16, 0, 0);
}

// DPP fetch within 16-lane row; VALU pipe.
template <int CTRL>
__device__ __forceinline__ float dpp_fetch(float x) {
    int xi = __builtin_bit_cast(int, x);
    int yi = __builtin_amdgcn_update_dpp(0, xi, CTRL, 0xF, 0xF, true);
    return __builtin_bit_cast(float, yi);
}
// butterfly sum over 16-lane group; result in ALL 16 lanes.
__device__ __forceinline__ float dpp_sum16(float p) {
    p += dpp_fetch<0xB1>(p);   // quad_perm xor1
    p += dpp_fetch<0x4E>(p);   // quad_perm xor2
    p += dpp_fetch<0x141>(p);  // row_half_mirror
    p += dpp_fetch<0x140>(p);  // row_mirror
    return p;
}

// block of 256 threads (4 waves). sbuf must be float[4] shared.
__device__ __forceinline__ float blk_reduce_sum(float x, float* sbuf) {
#pragma unroll
    for (int m = 32; m >= 1; m >>= 1) x += __shfl_xor(x, m);
    int wid = threadIdx.x >> 6;
    if ((threadIdx.x & 63) == 0) sbuf[wid] = x;
    __syncthreads();
    float t = sbuf[0] + sbuf[1] + sbuf[2] + sbuf[3];
    __syncthreads();
    return t;
}

// ---------------- fp32 -> bf16 cast (RNE), vector x4 ----------------
__global__ __launch_bounds__(256) void cast_bf16_kernel(
    const float* __restrict__ in, bf16_t* __restrict__ out, size_t n)
{
    size_t stride = (size_t)gridDim.x * 256 * 4;
    for (size_t i = ((size_t)blockIdx.x * 256 + threadIdx.x) * 4; i < n; i += stride) {
        float4 v = *reinterpret_cast<const float4*>(in + i);
        bfx4 o;
        o[0] = (bf16_t)v.x; o[1] = (bf16_t)v.y;
        o[2] = (bf16_t)v.z; o[3] = (bf16_t)v.w;
        *reinterpret_cast<bfx4*>(out + i) = o;
    }
}

// ---------------- embedding + layernorm ----------------

__global__ __launch_bounds__(256) void embed_ln_kernel(
    const int* __restrict__ src, const float* __restrict__ emb,
    const float* __restrict__ w, const float* __restrict__ b,
    float* __restrict__ R)
{
    __shared__ float sbuf[4];
    int row = blockIdx.x;
    int tok = src[row];
    const float* e = emb + (size_t)tok * D_MODEL;
    int c0 = threadIdx.x, c1 = threadIdx.x + 256;
    float v0 = e[c0], v1 = e[c1];
    float mu = blk_reduce_sum(v0 + v1, sbuf) * (1.0f / D_MODEL);
    float d0 = v0 - mu, d1 = v1 - mu;
    float var = blk_reduce_sum(d0 * d0 + d1 * d1, sbuf) * (1.0f / D_MODEL);
    float rs = rsqrtf(var + EPS);
    size_t base = (size_t)row * D_MODEL;
    R[base + c0] = d0 * rs * w[c0] + b[c0];
    R[base + c1] = d1 * rs * w[c1] + b[c1];
}

__global__ __launch_bounds__(256) void add_ln_kernel(
    float* __restrict__ R, const float* __restrict__ Hadd,
    const float* __restrict__ w, const float* __restrict__ b,
    float* __restrict__ out, bf16_t* __restrict__ outb)
{
    __shared__ float sbuf[4];
    size_t base = (size_t)blockIdx.x * D_MODEL;
    int c0 = threadIdx.x, c1 = c0 + 256;
    float v0 = R[base + c0], v1 = R[base + c1];
    if (Hadd) {
        v0 += Hadd[base + c0];
        v1 += Hadd[base + c1];
        R[base + c0] = v0;
        R[base + c1] = v1;
    }
    float mu = blk_reduce_sum(v0 + v1, sbuf) * (1.0f / D_MODEL);
    float d0 = v0 - mu, d1 = v1 - mu;
    float var = blk_reduce_sum(d0 * d0 + d1 * d1, sbuf) * (1.0f / D_MODEL);
    float rs = rsqrtf(var + EPS);
    float o0 = d0 * rs * w[c0] + b[c0];
    float o1 = d1 * rs * w[c1] + b[c1];
    if (out) {
        out[base + c0] = o0;
        out[base + c1] = o1;
    }
    if (outb) {
        outb[base + c0] = (bf16_t)o0;
        outb[base + c1] = (bf16_t)o1;
    }
}

// ---------------- bf16 MFMA GEMM (NT) ----------------
// EPI 0: C[row*ldc+col] = v (fp32)
// EPI 2: dt-path: v=softplus(v+bias[col]); pack {bf16(v), xcb[row,col]} -> dtx u32
// EPI 3: split store bf16: col<1024 -> Cxb, else -> Czb
template <int EPI>
__global__ __launch_bounds__(256) void gemm_bf16_nt(
    const bf16_t* __restrict__ A, const bf16_t* __restrict__ B,
    float* __restrict__ C, int ldc, int K, const float* __restrict__ bias,
    const unsigned short* __restrict__ xcb_u16,
    unsigned short* __restrict__ dtx_u16,
    bf16_t* __restrict__ Cxb, bf16_t* __restrict__ Czb)
{
    __shared__ bf16_t As[128 * 32];
    __shared__ bf16_t Bs[128 * 32];
    int tid = threadIdx.x;
    int lane = tid & 63, wid = tid >> 6;
    int m0 = blockIdx.y * 128, n0 = blockIdx.x * 128;
    int wm = (wid >> 1) * 64, wn = (wid & 1) * 64;
    int c_lo = lane & 15;
    int khalf = lane >> 4;

    f32x4 acc[4][4];
#pragma unroll
    for (int i = 0; i < 4; i++)
#pragma unroll
        for (int j = 0; j < 4; j++)
            acc[i][j] = (f32x4){0.f, 0.f, 0.f, 0.f};

    for (int k0 = 0; k0 < K; k0 += 32) {
#pragma unroll
        for (int i = 0; i < 2; i++) {
            int c = i * 256 + tid;
            int row = c >> 2;
            int cb = (c & 3) * 16;
            int ldsoff = (i * 256 + wid * 64) * 16;
            gload_lds16((const char*)A + ((size_t)(m0 + row) * K + k0) * 2 + cb,
                        (char*)As + ldsoff);
            gload_lds16((const char*)B + ((size_t)(n0 + row) * K + k0) * 2 + cb,
                        (char*)Bs + ldsoff);
        }
        __syncthreads();

        bfx8 af[4], bfr[4];
#pragma unroll
        for (int i = 0; i < 4; i++) {
            af[i]  = *reinterpret_cast<const bfx8*>(As + (wm + i * 16 + c_lo) * 32 + khalf * 8);
            bfr[i] = *reinterpret_cast<const bfx8*>(Bs + (wn + i * 16 + c_lo) * 32 + khalf * 8);
        }
#pragma unroll
        for (int i = 0; i < 4; i++)
#pragma unroll
            for (int j = 0; j < 4; j++)
                acc[i][j] = __builtin_amdgcn_mfma_f32_16x16x32_bf16(af[i], bfr[j], acc[i][j], 0, 0, 0);
        __syncthreads();
    }

#pragma unroll
    for (int i = 0; i < 4; i++) {
#pragma unroll
        for (int j = 0; j < 4; j++) {
            int row0 = m0 + wm + i * 16 + khalf * 4;
            int col = n0 + wn + j * 16 + c_lo;
#pragma unroll
            for (int r = 0; r < 4; r++) {
                int row = row0 + r;
                float v = acc[i][j][r];
                if (EPI == 0) {
                    C[(size_t)row * ldc + col] = v;
                } else if (EPI == 2) {
                    v = softplus_f(v + bias[col]);
                    unsigned int db = (unsigned int)__builtin_bit_cast(unsigned short, (bf16_t)v);
                    unsigned int xb = (unsigned int)xcb_u16[(size_t)row * D_INNER + col];
                    *(unsigned int*)(dtx_u16 + (size_t)row * 2048 + 2 * col) = db | (xb << 16);
                } else if (EPI == 3) {
                    if (col < D_INNER) Cxb[(size_t)row * D_INNER + col] = (bf16_t)v;
                    else               Czb[(size_t)row * D_INNER + col - D_INNER] = (bf16_t)v;
                }
            }
        }
    }
}

// ---------------- x_proj GEMM: xdbl = XCb(8192x1024) @ xw^T(64x1024) ----------------
// tile 64 rows x 64 cols, 128 threads (2 waves, 32 rows each).
// cols 0..31 (dt lowrank) -> XDlow bf16; cols 32..63 -> BCX f32 interleaved {B_s,C_s}.
__global__ __launch_bounds__(128) void gemm_xp_bf16(
    const bf16_t* __restrict__ A, const bf16_t* __restrict__ Bmat,
    bf16_t* __restrict__ XDlow, float* __restrict__ BCX, int K)
{
    __shared__ bf16_t As[64 * 32];
    __shared__ bf16_t Bs[64 * 32];
    int tid = threadIdx.x;
    int lane = tid & 63, w = tid >> 6;
    int m0 = blockIdx.x * 64;
    int wr0 = w * 32;
    int c_lo = lane & 15;
    int khalf = lane >> 4;

    f32x4 acc[2][4];
#pragma unroll
    for (int i = 0; i < 2; i++)
#pragma unroll
        for (int j = 0; j < 4; j++)
            acc[i][j] = (f32x4){0.f, 0.f, 0.f, 0.f};

    for (int k0 = 0; k0 < K; k0 += 32) {
#pragma unroll
        for (int call = 0; call < 2; call++) {
            int c = call * 128 + tid;
            int base = (call * 128 + w * 64) * 16;
            gload_lds16((const char*)A + ((size_t)(m0 + (c >> 2)) * K + k0) * 2 + (c & 3) * 16,
                        (char*)As + base);
            gload_lds16((const char*)Bmat + ((size_t)(c >> 2) * K + k0) * 2 + (c & 3) * 16,
                        (char*)Bs + base);
        }
        __syncthreads();

        bfx8 af[2], bfr[4];
#pragma unroll
        for (int i = 0; i < 2; i++)
            af[i] = *reinterpret_cast<const bfx8*>(As + (wr0 + i * 16 + c_lo) * 32 + khalf * 8);
#pragma unroll
        for (int j = 0; j < 4; j++)
            bfr[j] = *reinterpret_cast<const bfx8*>(Bs + (j * 16 + c_lo) * 32 + khalf * 8);
#pragma unroll
        for (int i = 0; i < 2; i++)
#pragma unroll
            for (int j = 0; j < 4; j++)
                acc[i][j] = __builtin_amdgcn_mfma_f32_16x16x32_bf16(af[i], bfr[j], acc[i][j], 0, 0, 0);
        __syncthreads();
    }

#pragma unroll
    for (int i = 0; i < 2; i++)
#pragma unroll
        for (int j = 0; j < 4; j++) {
            int row0 = m0 + wr0 + i * 16 + khalf * 4;
            int col = j * 16 + c_lo;
#pragma unroll
            for (int r = 0; r < 4; r++) {
                int row = row0 + r;
                float v = acc[i][j][r];
                if (col < DT_RANK) {
                    XDlow[(size_t)row * DT_RANK + col] = (bf16_t)v;
                } else {
                    int c2 = col - DT_RANK;
                    BCX[(size_t)row * 32 + 2 * (c2 & 15) + (c2 >> 4)] = v;
                }
            }
        }
}

// ---------------- causal depthwise conv + silu (bf16 in) -> bf16 ----------------
__global__ __launch_bounds__(256) void conv_silu_kernel(
    const bf16_t* __restrict__ Xrawb, const float* __restrict__ cw,
    const float* __restrict__ cb, bf16_t* __restrict__ XCb)
{
    size_t gid = (size_t)blockIdx.x * 256 + threadIdx.x;
    int d = (int)(gid & (D_INNER - 1));
    size_t bt = gid >> 10;
    int t = (int)(bt & (SEQ - 1));
    float acc = cb[d];
#pragma unroll
    for (int k = 0; k < D_CONV; k++) {
        int tt = t + k - (D_CONV - 1);
        if (tt >= 0)
            acc += cw[d * D_CONV + k] * (float)Xrawb[(bt + (size_t)(k - (D_CONV - 1))) * D_INNER + d];
    }
    XCb[gid] = (bf16_t)silu(acc);
}

// ---------------- staging helper for scan passes ----------------
// LDS slot layout (bytes): [0,2048) dtx (32 steps x 16ch u32), [2048,6144) bcx
// (32 steps x 32 f32). 256 threads; w = tid>>6, lane = tid&63.
__device__ __forceinline__ void scan_stage(
    char* base, const unsigned int* __restrict__ DTXb,
    const float* __restrict__ BCX, size_t r0, int d0, int w, int lane)
{
    if (w < 2) {
        int cdt = w * 64 + lane;  // dtx chunks 0..127
        gload_lds16((const char*)DTXb + ((r0 + (cdt >> 2)) * 1024 + d0) * 4 + (cdt & 3) * 16,
                    base + w * 1024);
        int cbc = 128 + w * 64;   // bcx chunks 128..255
        gload_lds16((const char*)BCX + (r0 + ((cbc + lane) >> 3)) * 128 + ((cbc + lane) & 7) * 16,
                    base + 2048 + cbc * 16);
    } else {
        int cbc = (w - 2) * 64;   // bcx chunks 0..127
        gload_lds16((const char*)BCX + (r0 + ((cbc + lane) >> 3)) * 128 + ((cbc + lane) & 7) * 16,
                    base + 2048 + cbc * 16);
    }
}

// ---------------- scan pass A: chunk summaries only ----------------
__global__ __launch_bounds__(256) void scan_pA_kernel(
    const unsigned int* __restrict__ DTXb, const float* __restrict__ BCX,
    const float* __restrict__ A_log,
    float* __restrict__ DcB, float* __restrict__ UcB)
{
    __shared__ __align__(16) char lds[2][6144];
    const int tid = threadIdx.x;
    const int w = tid >> 6, lane = tid & 63;
    const int s = tid & 15, dl = tid >> 4;
    const int b = blockIdx.x >> 6;
    const int d0 = (blockIdx.x & 63) * 16;
    const int c = blockIdx.y;
    const int d = d0 + dl;
    const float Av = -__expf(A_log[d * D_STATE + s]);
    const size_t bbase = (size_t)b * SEQ;
    const int tstart = c * CHUNK;

    float h = 0.f, cum = 0.f;
    scan_stage(lds[0], DTXb, BCX, bbase + tstart, d0, w, lane);
    __syncthreads();
    int cur = 0;
    for (int t0 = 0; t0 < CHUNK; t0 += 32) {
        if (t0 + 32 < CHUNK)
            scan_stage(lds[cur ^ 1], DTXb, BCX, bbase + tstart + t0 + 32, d0, w, lane);
        const char* L = lds[cur];
#pragma unroll
        for (int kk = 0; kk < 32; kk++) {
            unsigned int pk = *(const unsigned int*)(L + kk * 64 + dl * 4);
            float dtv = __builtin_bit_cast(float, pk << 16);
            float xv  = __builtin_bit_cast(float, pk & 0xFFFF0000u);
            float bv  = *(const float*)(L + 2048 + kk * 128 + s * 8);
            float e = __expf(dtv * Av);
            h = fmaf(e, h, dtv * xv * bv);
            cum += dtv;
        }
        __syncthreads();
        cur ^= 1;
    }
    size_t cb64 = ((size_t)c * B_SZ + b) * D_INNER + d;
    UcB[cb64 * 16 + s] = h;
    if (s == 0) DcB[cb64] = cum;
}

// ---------------- scan pass 2: serial chunk-state propagation ----------------
__global__ __launch_bounds__(256) void scan_p2_kernel(
    const float* __restrict__ A_log, const float* __restrict__ DcB,
    const float* __restrict__ UcB, float* __restrict__ HcB)
{
    int tid = threadIdx.x;
    int s = tid & 15, dl = tid >> 4;
    int chain = blockIdx.x * 16 + dl;
    int b = chain >> 10, d = chain & 1023;
    float Av = -__expf(A_log[d * D_STATE + s]);
    float Hv = 0.f;
    for (int c = 0; c < NCHUNK; c++) {
        size_t base = ((size_t)c * B_SZ + b) * D_INNER + d;
        HcB[base * 16 + s] = Hv;   // state at START of chunk c
        Hv = __expf(Av * DcB[base]) * Hv + UcB[base * 16 + s];
    }
}

// ---------------- scan pass B: recompute from chunk-start state, fused combine ----
__global__ __launch_bounds__(256) void scan_pB_kernel(
    const unsigned int* __restrict__ DTXb, const float* __restrict__ BCX,
    const float* __restrict__ HcB, const float* __restrict__ A_log,
    const bf16_t* __restrict__ Zbufb, const float* __restrict__ Dskip,
    bf16_t* __restrict__ XCb)
{
    __shared__ __align__(16) char lds[2][6144];
    __shared__ float ytile[32][17];
    const int tid = threadIdx.x;
    const int w = tid >> 6, lane = tid & 63;
    const int s = tid & 15, dl = tid >> 4;
    const int b = blockIdx.x >> 6;
    const int d0 = (blockIdx.x & 63) * 16;
    const int c = blockIdx.y;
    const int d = d0 + dl;
    const float Av = -__expf(A_log[d * D_STATE + s]);
    const size_t bbase = (size_t)b * SEQ;
    const int tstart = c * CHUNK;

    float h = HcB[(((size_t)c * B_SZ + b) * D_INNER + d) * 16 + s];

    // combine-phase per-thread constants: idx = tid*2 over [32 t][16 d] tile
    const int tl  = tid >> 3;            // 0..31
    const int dlo = (tid * 2) & 15;      // even
    const float dsk0 = Dskip[d0 + dlo];
    const float dsk1 = Dskip[d0 + dlo + 1];

    scan_stage(lds[0], DTXb, BCX, bbase + tstart, d0, w, lane);
    __syncthreads();
    int cur = 0;
    for (int t0 = 0; t0 < CHUNK; t0 += 32) {
        if (t0 + 32 < CHUNK)
            scan_stage(lds[cur ^ 1], DTXb, BCX, bbase + tstart + t0 + 32, d0, w, lane);
        const char* L = lds[cur];
#pragma unroll
        for (int half = 0; half < 2; half++) {
            float yhold = 0.f;
#pragma unroll
            for (int k = 0; k < 16; k++) {
                int kk = half * 16 + k;
                unsigned int pk = *(const unsigned int*)(L + kk * 64 + dl * 4);
                float dtv = __builtin_bit_cast(float, pk << 16);
                float xv  = __builtin_bit_cast(float, pk & 0xFFFF0000u);
                float2 bc = *(const float2*)(L + 2048 + kk * 128 + s * 8);
                float e = __expf(dtv * Av);
                h = fmaf(e, h, dtv * xv * bc.x);
                float p = dpp_sum16(h * bc.y);
                if (s == k) yhold = p;
            }
            ytile[half * 16 + s][dl] = yhold;
        }
        __syncthreads();

        // combine + coalesced store: thread handles (t = t0+tl, d = d0+dlo, +1)
        {
            int t = tstart + t0 + tl;
            size_t row = (bbase + t) * (size_t)D_INNER + d0 + dlo;
            float y0 = ytile[tl][dlo];
            float y1 = ytile[tl][dlo + 1];
            unsigned int xw = *(const unsigned int*)(XCb + row);
            float x0 = __builtin_bit_cast(float, xw << 16);
            float x1 = __builtin_bit_cast(float, xw & 0xFFFF0000u);
            unsigned int zw = *(const unsigned int*)(Zbufb + row);
            float z0 = __builtin_bit_cast(float, zw << 16);
            float z1 = __builtin_bit_cast(float, zw & 0xFFFF0000u);
            float g0 = (y0 + x0 * dsk0) * silu(z0);
            float g1 = (y1 + x1 * dsk1) * silu(z1);
            unsigned int o = (unsigned int)__builtin_bit_cast(unsigned short, (bf16_t)g0)
                           | ((unsigned int)__builtin_bit_cast(unsigned short, (bf16_t)g1) << 16);
            *(unsigned int*)(XCb + row) = o;
        }
        __syncthreads();
        cur ^= 1;
    }
}

// ---------------- launch ----------------

extern "C" void kernel_launch(void* const* d_in, const int* in_sizes, int n_in,
                              void* d_out, int out_size, void* d_ws, size_t ws_size,
                              hipStream_t stream) {
    const int*   src       = (const int*)d_in[0];
    const float* emb_w     = (const float*)d_in[2];
    const float* enc_ln_w  = (const float*)d_in[3];
    const float* enc_ln_b  = (const float*)d_in[4];
    const float* ln_w      = (const float*)d_in[5];
    const float* ln_b      = (const float*)d_in[6];
    const float* in_proj_w = (const float*)d_in[7];
    const float* conv_w    = (const float*)d_in[8];
    const float* conv_b    = (const float*)d_in[9];
    const float* x_proj_w  = (const float*)d_in[10];
    const float* dt_proj_w = (const float*)d_in[11];
    const float* dt_proj_b = (const float*)d_in[12];
    const float* A_log     = (const float*)d_in[13];
    const float* D_skip    = (const float*)d_in[14];
    const float* out_proj_w= (const float*)d_in[15];
    const float* normf_w   = (const float*)d_in[16];
    const float* normf_b   = (const float*)d_in[17];
    float* out = (float*)d_out;

    // fp32 scratch
    float* R    = (float*)d_ws;
    float* H    = R    + (size_t)NROWS * D_MODEL;
    float* BCX  = H    + (size_t)NROWS * D_MODEL;      // 8192*32, {B,C} interleaved
    float* DcB  = BCX  + (size_t)NROWS * 32;
    float* UcB  = DcB  + (size_t)NCHUNK * B_SZ * D_INNER;
    float* HcB  = UcB  + (size_t)NCHUNK * B_SZ * D_INNER * D_STATE;
    // bf16 / packed scratch
    bf16_t* Hb    = (bf16_t*)(HcB + (size_t)NCHUNK * B_SZ * D_INNER * D_STATE);
    bf16_t* Xrawb = Hb    + (size_t)NROWS * D_MODEL;
    bf16_t* Zbufb = Xrawb + (size_t)NROWS * D_INNER;
    bf16_t* XCb   = Zbufb + (size_t)NROWS * D_INNER;
    bf16_t* XDlow = XCb   + (size_t)NROWS * D_INNER;               // 8192*32
    unsigned short* DTXb = (unsigned short*)(XDlow + (size_t)NROWS * DT_RANK);
    bf16_t* Wib   = (bf16_t*)(DTXb + (size_t)NROWS * 2048);
    bf16_t* Wob   = Wib   + (size_t)NLAYERS * 2 * D_INNER * D_MODEL;
    bf16_t* xpb   = Wob   + (size_t)NLAYERS * D_MODEL * D_INNER;   // 4*64*1024
    bf16_t* dtwb  = xpb   + (size_t)NLAYERS * 64 * D_INNER;        // 4*1024*32

    // one-time weight prep
    cast_bf16_kernel<<<2048, 256, 0, stream>>>(in_proj_w, Wib, (size_t)NLAYERS * 2 * D_INNER * D_MODEL);
    cast_bf16_kernel<<<2048, 256, 0, stream>>>(out_proj_w, Wob, (size_t)NLAYERS * D_MODEL * D_INNER);
    cast_bf16_kernel<<<256, 256, 0, stream>>>(x_proj_w, xpb, (size_t)NLAYERS * 64 * D_INNER);
    cast_bf16_kernel<<<128, 256, 0, stream>>>(dt_proj_w, dtwb, (size_t)NLAYERS * D_INNER * DT_RANK);

    embed_ln_kernel<<<NROWS, 256, 0, stream>>>(src, emb_w, enc_ln_w, enc_ln_b, R);

    for (int L = 0; L < NLAYERS; L++) {
        const float* AlogL = A_log + (size_t)L * D_INNER * D_STATE;

        add_ln_kernel<<<NROWS, 256, 0, stream>>>(
            R, (L == 0) ? nullptr : H, ln_w + L * D_MODEL, ln_b + L * D_MODEL,
            nullptr, Hb);

        // in_proj -> Xrawb (x half, bf16), Zbufb (z half, bf16)
        gemm_bf16_nt<3><<<dim3(16, 64), 256, 0, stream>>>(
            Hb, Wib + (size_t)L * 2 * D_INNER * D_MODEL, nullptr, 0, D_MODEL,
            nullptr, nullptr, nullptr, Xrawb, Zbufb);

        conv_silu_kernel<<<(NROWS * D_INNER) / 256, 256, 0, stream>>>(
            Xrawb, conv_w + (size_t)L * D_INNER * D_CONV, conv_b + (size_t)L * D_INNER, XCb);

        // x_proj: dt lowrank (bf16) + B/C interleaved (f32)
        gemm_xp_bf16<<<NROWS / 64, 128, 0, stream>>>(
            XCb, xpb + (size_t)L * 64 * D_INNER, XDlow, BCX, D_INNER);

        // dt_proj (K=32) + softplus + pack {dt,x} -> DTXb
        gemm_bf16_nt<2><<<dim3(8, 64), 256, 0, stream>>>(
            XDlow, dtwb + (size_t)L * D_INNER * DT_RANK, nullptr, 0, DT_RANK,
            dt_proj_b + (size_t)L * D_INNER, (const unsigned short*)XCb, DTXb,
            nullptr, nullptr);

        // chunked scan: summaries -> propagate -> recompute+combine
        scan_pA_kernel<<<dim3(B_SZ * 64, NCHUNK), 256, 0, stream>>>(
            (const unsigned int*)DTXb, BCX, AlogL, DcB, UcB);
        scan_p2_kernel<<<256, 256, 0, stream>>>(AlogL, DcB, UcB, HcB);
        scan_pB_kernel<<<dim3(B_SZ * 64, NCHUNK), 256, 0, stream>>>(
            (const unsigned int*)DTXb, BCX, HcB, AlogL, Zbufb,
            D_skip + (size_t)L * D_INNER, XCb);

        // out_proj
        gemm_bf16_nt<0><<<dim3(4, 64), 256, 0, stream>>>(
            XCb, Wob + (size_t)L * D_MODEL * D_INNER, H, D_MODEL, D_INNER,
            nullptr, nullptr, nullptr, nullptr, nullptr);
    }

    add_ln_kernel<<<NROWS, 256, 0, stream>>>(R, H, normf_w, normf_b, out, nullptr);
}

// Round 8
// 1084.111 us; speedup vs baseline: 1.4697x; 1.0066x over previous
//
#include <hip/hip_runtime.h>
#include <hip/hip_bf16.h>
#include <math.h>

#define NTOKEN 60697
#define D_MODEL 512
#define NLAYERS 4
#define D_STATE 16
#define D_CONV 4
#define D_INNER 1024
#define DT_RANK 32
#define B_SZ 4
#define SEQ 2048
#define EPS 1e-5f
#define NROWS (B_SZ * SEQ)   // 8192
#define CHUNK 128
#define NCHUNK (SEQ / CHUNK) // 16
#define LOG2E 1.44269504f

typedef __bf16 bf16_t;
typedef __attribute__((ext_vector_type(8))) __bf16 bfx8;
typedef __attribute__((ext_vector_type(4))) __bf16 bfx4;
typedef __attribute__((ext_vector_type(4))) float f32x4;

// ---------------- utilities ----------------

__device__ __forceinline__ float fast_sigmoid(float x) {
    return 1.0f / (1.0f + __expf(-x));
}
__device__ __forceinline__ float silu(float x) {
    return x * fast_sigmoid(x);
}
__device__ __forceinline__ float softplus_f(float x) {
    return (x > 20.0f) ? x : log1pf(__expf(x));
}
__device__ __forceinline__ float exp2_fast(float x) {
    float r;
    asm("v_exp_f32 %0, %1" : "=v"(r) : "v"(x));
    return r;
}
__device__ __forceinline__ unsigned int bf16bits(float v) {
    return (unsigned int)__builtin_bit_cast(unsigned short, (bf16_t)v);
}
__device__ __forceinline__ float lo16f(unsigned int u) {
    return __builtin_bit_cast(float, u << 16);
}
__device__ __forceinline__ float hi16f(unsigned int u) {
    return __builtin_bit_cast(float, u & 0xFFFF0000u);
}

__device__ __forceinline__ void gload_lds16(const void* g, void* l) {
    __builtin_amdgcn_global_load_lds(
        (const __attribute__((address_space(1))) unsigned int*)g,
        (__attribute__((address_space(3))) unsigned int*)l, 16, 0, 0);
}

// DPP fetch within 16-lane row; VALU pipe.
template <int CTRL>
__device__ __forceinline__ float dpp_fetch(float x) {
    int xi = __builtin_bit_cast(int, x);
    int yi = __builtin_amdgcn_update_dpp(0, xi, CTRL, 0xF, 0xF, true);
    return __builtin_bit_cast(float, yi);
}
// butterfly sum over 16-lane group; result in ALL 16 lanes.
__device__ __forceinline__ float dpp_sum16(float p) {
    p += dpp_fetch<0xB1>(p);   // quad_perm xor1
    p += dpp_fetch<0x4E>(p);   // quad_perm xor2
    p += dpp_fetch<0x141>(p);  // row_half_mirror
    p += dpp_fetch<0x140>(p);  // row_mirror
    return p;
}

// block of 256 threads (4 waves). sbuf must be float[4] shared.
__device__ __forceinline__ float blk_reduce_sum(float x, float* sbuf) {
#pragma unroll
    for (int m = 32; m >= 1; m >>= 1) x += __shfl_xor(x, m);
    int wid = threadIdx.x >> 6;
    if ((threadIdx.x & 63) == 0) sbuf[wid] = x;
    __syncthreads();
    float t = sbuf[0] + sbuf[1] + sbuf[2] + sbuf[3];
    __syncthreads();
    return t;
}

// ---------------- fp32 -> bf16 cast (RNE), vector x4 ----------------
__global__ __launch_bounds__(256) void cast_bf16_kernel(
    const float* __restrict__ in, bf16_t* __restrict__ out, size_t n)
{
    size_t stride = (size_t)gridDim.x * 256 * 4;
    for (size_t i = ((size_t)blockIdx.x * 256 + threadIdx.x) * 4; i < n; i += stride) {
        float4 v = *reinterpret_cast<const float4*>(in + i);
        bfx4 o;
        o[0] = (bf16_t)v.x; o[1] = (bf16_t)v.y;
        o[2] = (bf16_t)v.z; o[3] = (bf16_t)v.w;
        *reinterpret_cast<bfx4*>(out + i) = o;
    }
}

// ---------------- embedding + layernorm ----------------

__global__ __launch_bounds__(256) void embed_ln_kernel(
    const int* __restrict__ src, const float* __restrict__ emb,
    const float* __restrict__ w, const float* __restrict__ b,
    float* __restrict__ R)
{
    __shared__ float sbuf[4];
    int row = blockIdx.x;
    int tok = src[row];
    const float* e = emb + (size_t)tok * D_MODEL;
    int c0 = threadIdx.x, c1 = threadIdx.x + 256;
    float v0 = e[c0], v1 = e[c1];
    float mu = blk_reduce_sum(v0 + v1, sbuf) * (1.0f / D_MODEL);
    float d0 = v0 - mu, d1 = v1 - mu;
    float var = blk_reduce_sum(d0 * d0 + d1 * d1, sbuf) * (1.0f / D_MODEL);
    float rs = rsqrtf(var + EPS);
    size_t base = (size_t)row * D_MODEL;
    R[base + c0] = d0 * rs * w[c0] + b[c0];
    R[base + c1] = d1 * rs * w[c1] + b[c1];
}

__global__ __launch_bounds__(256) void add_ln_kernel(
    float* __restrict__ R, const float* __restrict__ Hadd,
    const float* __restrict__ w, const float* __restrict__ b,
    float* __restrict__ out, bf16_t* __restrict__ outb)
{
    __shared__ float sbuf[4];
    size_t base = (size_t)blockIdx.x * D_MODEL;
    int c0 = threadIdx.x, c1 = c0 + 256;
    float v0 = R[base + c0], v1 = R[base + c1];
    if (Hadd) {
        v0 += Hadd[base + c0];
        v1 += Hadd[base + c1];
        R[base + c0] = v0;
        R[base + c1] = v1;
    }
    float mu = blk_reduce_sum(v0 + v1, sbuf) * (1.0f / D_MODEL);
    float d0 = v0 - mu, d1 = v1 - mu;
    float var = blk_reduce_sum(d0 * d0 + d1 * d1, sbuf) * (1.0f / D_MODEL);
    float rs = rsqrtf(var + EPS);
    float o0 = d0 * rs * w[c0] + b[c0];
    float o1 = d1 * rs * w[c1] + b[c1];
    if (out) {
        out[base + c0] = o0;
        out[base + c1] = o1;
    }
    if (outb) {
        outb[base + c0] = (bf16_t)o0;
        outb[base + c1] = (bf16_t)o1;
    }
}

// ---------------- bf16 MFMA GEMM (NT) ----------------
// EPI 0: C[row*ldc+col] = v (fp32)
// EPI 2: dt-path: v=softplus(v+bias[col]); pack {bf16(v), bf16(v*x)} pair-interleaved
// EPI 3: split store bf16: col<1024 -> Cxb, else -> Czb
template <int EPI>
__global__ __launch_bounds__(256) void gemm_bf16_nt(
    const bf16_t* __restrict__ A, const bf16_t* __restrict__ B,
    float* __restrict__ C, int ldc, int K, const float* __restrict__ bias,
    const unsigned short* __restrict__ xcb_u16,
    unsigned int* __restrict__ dtx_u32,
    bf16_t* __restrict__ Cxb, bf16_t* __restrict__ Czb)
{
    __shared__ bf16_t As[128 * 32];
    __shared__ bf16_t Bs[128 * 32];
    int tid = threadIdx.x;
    int lane = tid & 63, wid = tid >> 6;
    int m0 = blockIdx.y * 128, n0 = blockIdx.x * 128;
    int wm = (wid >> 1) * 64, wn = (wid & 1) * 64;
    int c_lo = lane & 15;
    int khalf = lane >> 4;

    f32x4 acc[4][4];
#pragma unroll
    for (int i = 0; i < 4; i++)
#pragma unroll
        for (int j = 0; j < 4; j++)
            acc[i][j] = (f32x4){0.f, 0.f, 0.f, 0.f};

    for (int k0 = 0; k0 < K; k0 += 32) {
#pragma unroll
        for (int i = 0; i < 2; i++) {
            int c = i * 256 + tid;
            int row = c >> 2;
            int cb = (c & 3) * 16;
            int ldsoff = (i * 256 + wid * 64) * 16;
            gload_lds16((const char*)A + ((size_t)(m0 + row) * K + k0) * 2 + cb,
                        (char*)As + ldsoff);
            gload_lds16((const char*)B + ((size_t)(n0 + row) * K + k0) * 2 + cb,
                        (char*)Bs + ldsoff);
        }
        __syncthreads();

        bfx8 af[4], bfr[4];
#pragma unroll
        for (int i = 0; i < 4; i++) {
            af[i]  = *reinterpret_cast<const bfx8*>(As + (wm + i * 16 + c_lo) * 32 + khalf * 8);
            bfr[i] = *reinterpret_cast<const bfx8*>(Bs + (wn + i * 16 + c_lo) * 32 + khalf * 8);
        }
#pragma unroll
        for (int i = 0; i < 4; i++)
#pragma unroll
            for (int j = 0; j < 4; j++)
                acc[i][j] = __builtin_amdgcn_mfma_f32_16x16x32_bf16(af[i], bfr[j], acc[i][j], 0, 0, 0);
        __syncthreads();
    }

#pragma unroll
    for (int i = 0; i < 4; i++) {
#pragma unroll
        for (int j = 0; j < 4; j++) {
            int row0 = m0 + wm + i * 16 + khalf * 4;
            int col = n0 + wn + j * 16 + c_lo;
#pragma unroll
            for (int r = 0; r < 4; r++) {
                int row = row0 + r;
                float v = acc[i][j][r];
                if (EPI == 0) {
                    C[(size_t)row * ldc + col] = v;
                } else if (EPI == 2) {
                    v = softplus_f(v + bias[col]);
                    float xf = lo16f((unsigned int)xcb_u16[(size_t)row * D_INNER + col]);
                    unsigned int u = bf16bits(v) | (bf16bits(v * xf) << 16);
                    dtx_u32[(size_t)(row >> 1) * 2048 + col * 2 + (row & 1)] = u;
                } else if (EPI == 3) {
                    if (col < D_INNER) Cxb[(size_t)row * D_INNER + col] = (bf16_t)v;
                    else               Czb[(size_t)row * D_INNER + col - D_INNER] = (bf16_t)v;
                }
            }
        }
    }
}

// ---------------- x_proj GEMM: xdbl = XCb(8192x1024) @ xw^T(64x1024) ----------------
// cols 0..31 -> XDlow bf16; cols 32..63 -> BCb bf16-packed {B,C} pair-interleaved.
__global__ __launch_bounds__(128) void gemm_xp_bf16(
    const bf16_t* __restrict__ A, const bf16_t* __restrict__ Bmat,
    bf16_t* __restrict__ XDlow, unsigned int* __restrict__ BCb, int K)
{
    __shared__ bf16_t As[64 * 32];
    __shared__ bf16_t Bs[64 * 32];
    int tid = threadIdx.x;
    int lane = tid & 63, w = tid >> 6;
    int m0 = blockIdx.x * 64;
    int wr0 = w * 32;
    int c_lo = lane & 15;
    int khalf = lane >> 4;

    f32x4 acc[2][4];
#pragma unroll
    for (int i = 0; i < 2; i++)
#pragma unroll
        for (int j = 0; j < 4; j++)
            acc[i][j] = (f32x4){0.f, 0.f, 0.f, 0.f};

    for (int k0 = 0; k0 < K; k0 += 32) {
#pragma unroll
        for (int call = 0; call < 2; call++) {
            int c = call * 128 + tid;
            int base = (call * 128 + w * 64) * 16;
            gload_lds16((const char*)A + ((size_t)(m0 + (c >> 2)) * K + k0) * 2 + (c & 3) * 16,
                        (char*)As + base);
            gload_lds16((const char*)Bmat + ((size_t)(c >> 2) * K + k0) * 2 + (c & 3) * 16,
                        (char*)Bs + base);
        }
        __syncthreads();

        bfx8 af[2], bfr[4];
#pragma unroll
        for (int i = 0; i < 2; i++)
            af[i] = *reinterpret_cast<const bfx8*>(As + (wr0 + i * 16 + c_lo) * 32 + khalf * 8);
#pragma unroll
        for (int j = 0; j < 4; j++)
            bfr[j] = *reinterpret_cast<const bfx8*>(Bs + (j * 16 + c_lo) * 32 + khalf * 8);
#pragma unroll
        for (int i = 0; i < 2; i++)
#pragma unroll
            for (int j = 0; j < 4; j++)
                acc[i][j] = __builtin_amdgcn_mfma_f32_16x16x32_bf16(af[i], bfr[j], acc[i][j], 0, 0, 0);
        __syncthreads();
    }

#pragma unroll
    for (int i = 0; i < 2; i++) {
        int row0 = m0 + wr0 + i * 16 + khalf * 4;
#pragma unroll
        for (int r = 0; r < 4; r++) {
            int row = row0 + r;
            XDlow[(size_t)row * DT_RANK + c_lo]      = (bf16_t)acc[i][0][r];
            XDlow[(size_t)row * DT_RANK + 16 + c_lo] = (bf16_t)acc[i][1][r];
            unsigned int u = bf16bits(acc[i][2][r]) | (bf16bits(acc[i][3][r]) << 16);
            BCb[(size_t)(row >> 1) * 32 + c_lo * 2 + (row & 1)] = u;
        }
    }
}

// ---------------- causal depthwise conv + silu (bf16 in) -> bf16 ----------------
__global__ __launch_bounds__(256) void conv_silu_kernel(
    const bf16_t* __restrict__ Xrawb, const float* __restrict__ cw,
    const float* __restrict__ cb, bf16_t* __restrict__ XCb)
{
    size_t gid = (size_t)blockIdx.x * 256 + threadIdx.x;
    int d = (int)(gid & (D_INNER - 1));
    size_t bt = gid >> 10;
    int t = (int)(bt & (SEQ - 1));
    float acc = cb[d];
#pragma unroll
    for (int k = 0; k < D_CONV; k++) {
        int tt = t + k - (D_CONV - 1);
        if (tt >= 0)
            acc += cw[d * D_CONV + k] * (float)Xrawb[(bt + (size_t)(k - (D_CONV - 1))) * D_INNER + d];
    }
    XCb[gid] = (bf16_t)silu(acc);
}

// ---------------- staging for 64-step tiles ----------------
// slot (8KB): [0,4096) dtx: [pair][16 d][2] u32; [4096,8192) bcb: [pair][16 s][2] u32
__device__ __forceinline__ void scan_stage64(
    char* base, const unsigned int* __restrict__ DTXp,
    const unsigned int* __restrict__ BCp, size_t rowpair0, int d0, int tid)
{
    gload_lds16(DTXp + (rowpair0 + (size_t)(tid >> 3)) * 2048 + d0 * 2 + (tid & 7) * 4,
                base + tid * 16);
    gload_lds16(BCp + rowpair0 * 32 + tid * 4, base + 4096 + tid * 16);
}

// ---------------- scan pass A: chunk summaries only ----------------
__global__ __launch_bounds__(256) void scan_pA_kernel(
    const unsigned int* __restrict__ DTXb, const unsigned int* __restrict__ BCb,
    const float* __restrict__ A_log,
    float* __restrict__ DcB, float* __restrict__ UcB)
{
    __shared__ __align__(16) char lds[2][8192];
    const int tid = threadIdx.x;
    const int s = tid & 15, dl = tid >> 4;
    const int b = blockIdx.x >> 6;
    const int d0 = (blockIdx.x & 63) * 16;
    const int c = blockIdx.y;
    const int d = d0 + dl;
    const float Av2 = -__expf(A_log[d * D_STATE + s]) * LOG2E;
    const size_t bbase = (size_t)b * SEQ;
    const int tstart = c * CHUNK;

    float h = 0.f, cum = 0.f;
    scan_stage64(lds[0], DTXb, BCb, (bbase + tstart) >> 1, d0, tid);
    __syncthreads();
    int cur = 0;
    for (int t0 = 0; t0 < CHUNK; t0 += 64) {
        if (t0 + 64 < CHUNK)
            scan_stage64(lds[cur ^ 1], DTXb, BCb, (bbase + tstart + t0 + 64) >> 1, d0, tid);
        const char* L = lds[cur];
#pragma unroll
        for (int kk2 = 0; kk2 < 32; kk2++) {
            uint2 dp = *(const uint2*)(L + kk2 * 128 + dl * 8);
            uint2 bp = *(const uint2*)(L + 4096 + kk2 * 128 + s * 8);
#pragma unroll
            for (int j = 0; j < 2; j++) {
                unsigned int pk = j ? dp.y : dp.x;
                unsigned int bk = j ? bp.y : bp.x;
                float dtv = lo16f(pk);
                float ux  = hi16f(pk);
                float bv  = lo16f(bk);
                float e = exp2_fast(dtv * Av2);
                h = fmaf(e, h, ux * bv);
                cum += dtv;
            }
        }
        __syncthreads();
        cur ^= 1;
    }
    size_t cb64 = ((size_t)c * B_SZ + b) * D_INNER + d;
    UcB[cb64 * 16 + s] = h;
    if (s == 0) DcB[cb64] = cum;
}

// ---------------- scan pass 2: serial chunk-state propagation ----------------
__global__ __launch_bounds__(256) void scan_p2_kernel(
    const float* __restrict__ A_log, const float* __restrict__ DcB,
    const float* __restrict__ UcB, float* __restrict__ HcB)
{
    int tid = threadIdx.x;
    int s = tid & 15, dl = tid >> 4;
    int chain = blockIdx.x * 16 + dl;
    int b = chain >> 10, d = chain & 1023;
    float Av = -__expf(A_log[d * D_STATE + s]);
    float Hv = 0.f;
    for (int c = 0; c < NCHUNK; c++) {
        size_t base = ((size_t)c * B_SZ + b) * D_INNER + d;
        HcB[base * 16 + s] = Hv;   // state at START of chunk c
        Hv = __expf(Av * DcB[base]) * Hv + UcB[base * 16 + s];
    }
}

// ---------------- scan pass B: recompute from chunk-start state, fused combine ----
__global__ __launch_bounds__(256) void scan_pB_kernel(
    const unsigned int* __restrict__ DTXb, const unsigned int* __restrict__ BCb,
    const float* __restrict__ HcB, const float* __restrict__ A_log,
    const bf16_t* __restrict__ Zbufb, const float* __restrict__ Dskip,
    bf16_t* __restrict__ XCb)
{
    __shared__ __align__(16) char lds[2][8192];
    __shared__ float ytile[32][17];
    const int tid = threadIdx.x;
    const int s = tid & 15, dl = tid >> 4;
    const int b = blockIdx.x >> 6;
    const int d0 = (blockIdx.x & 63) * 16;
    const int c = blockIdx.y;
    const int d = d0 + dl;
    const float Av2 = -__expf(A_log[d * D_STATE + s]) * LOG2E;
    const size_t bbase = (size_t)b * SEQ;
    const int tstart = c * CHUNK;

    float h = HcB[(((size_t)c * B_SZ + b) * D_INNER + d) * 16 + s];

    // combine-phase constants: thread -> (tl, dlo pair) over [32 t][16 d] tile
    const int tl  = tid >> 3;
    const int dlo = (tid * 2) & 15;
    const float dsk0 = Dskip[d0 + dlo];
    const float dsk1 = Dskip[d0 + dlo + 1];

    scan_stage64(lds[0], DTXb, BCb, (bbase + tstart) >> 1, d0, tid);
    __syncthreads();
    int cur = 0;
    for (int t0 = 0; t0 < CHUNK; t0 += 64) {
        if (t0 + 64 < CHUNK)
            scan_stage64(lds[cur ^ 1], DTXb, BCb, (bbase + tstart + t0 + 64) >> 1, d0, tid);
        const char* L = lds[cur];
#pragma unroll
        for (int g = 0; g < 2; g++) {           // two 32-step groups per tile
#pragma unroll
            for (int half = 0; half < 2; half++) {  // 16-step sub-groups
                float yhold = 0.f;
#pragma unroll
                for (int k8 = 0; k8 < 8; k8++) {
                    int kk2 = g * 16 + half * 8 + k8;
                    uint2 dp = *(const uint2*)(L + kk2 * 128 + dl * 8);
                    uint2 bp = *(const uint2*)(L + 4096 + kk2 * 128 + s * 8);
#pragma unroll
                    for (int j = 0; j < 2; j++) {
                        unsigned int pk = j ? dp.y : dp.x;
                        unsigned int bk = j ? bp.y : bp.x;
                        float dtv = lo16f(pk);
                        float ux  = hi16f(pk);
                        float bv  = lo16f(bk);
                        float cv  = hi16f(bk);
                        float e = exp2_fast(dtv * Av2);
                        h = fmaf(e, h, ux * bv);
                        float p = dpp_sum16(h * cv);
                        if (s == k8 * 2 + j + half * 0) { /* placeholder */ }
                        int k16 = k8 * 2 + j;
                        if (s == k16) yhold = p;
                    }
                }
                ytile[half * 16 + s][dl] = yhold;
            }
            __syncthreads();   // ytile ready
            {
                int t = tstart + t0 + g * 32 + tl;
                size_t row = (bbase + t) * (size_t)D_INNER + d0 + dlo;
                float y0 = ytile[tl][dlo];
                float y1 = ytile[tl][dlo + 1];
                unsigned int xw = *(const unsigned int*)(XCb + row);
                unsigned int zw = *(const unsigned int*)(Zbufb + row);
                float g0 = (y0 + lo16f(xw) * dsk0) * silu(lo16f(zw));
                float g1 = (y1 + hi16f(xw) * dsk1) * silu(hi16f(zw));
                unsigned int o = bf16bits(g0) | (bf16bits(g1) << 16);
                *(unsigned int*)(XCb + row) = o;
            }
            __syncthreads();   // ytile consumed
        }
        cur ^= 1;
    }
}

// ---------------- launch ----------------

extern "C" void kernel_launch(void* const* d_in, const int* in_sizes, int n_in,
                              void* d_out, int out_size, void* d_ws, size_t ws_size,
                              hipStream_t stream) {
    const int*   src       = (const int*)d_in[0];
    const float* emb_w     = (const float*)d_in[2];
    const float* enc_ln_w  = (const float*)d_in[3];
    const float* enc_ln_b  = (const float*)d_in[4];
    const float* ln_w      = (const float*)d_in[5];
    const float* ln_b      = (const float*)d_in[6];
    const float* in_proj_w = (const float*)d_in[7];
    const float* conv_w    = (const float*)d_in[8];
    const float* conv_b    = (const float*)d_in[9];
    const float* x_proj_w  = (const float*)d_in[10];
    const float* dt_proj_w = (const float*)d_in[11];
    const float* dt_proj_b = (const float*)d_in[12];
    const float* A_log     = (const float*)d_in[13];
    const float* D_skip    = (const float*)d_in[14];
    const float* out_proj_w= (const float*)d_in[15];
    const float* normf_w   = (const float*)d_in[16];
    const float* normf_b   = (const float*)d_in[17];
    float* out = (float*)d_out;

    // fp32 scratch
    float* R    = (float*)d_ws;
    float* H    = R    + (size_t)NROWS * D_MODEL;
    float* DcB  = H    + (size_t)NROWS * D_MODEL;
    float* UcB  = DcB  + (size_t)NCHUNK * B_SZ * D_INNER;
    float* HcB  = UcB  + (size_t)NCHUNK * B_SZ * D_INNER * D_STATE;
    // packed scratch
    unsigned int* BCb = (unsigned int*)(HcB + (size_t)NCHUNK * B_SZ * D_INNER * D_STATE);  // 4096*32 u32
    unsigned int* DTXb = BCb + (size_t)(NROWS / 2) * 32;   // 4096*2048 u32
    bf16_t* Hb    = (bf16_t*)(DTXb + (size_t)(NROWS / 2) * 2048);
    bf16_t* Xrawb = Hb    + (size_t)NROWS * D_MODEL;
    bf16_t* Zbufb = Xrawb + (size_t)NROWS * D_INNER;
    bf16_t* XCb   = Zbufb + (size_t)NROWS * D_INNER;
    bf16_t* XDlow = XCb   + (size_t)NROWS * D_INNER;               // 8192*32
    bf16_t* Wib   = XDlow + (size_t)NROWS * DT_RANK;
    bf16_t* Wob   = Wib   + (size_t)NLAYERS * 2 * D_INNER * D_MODEL;
    bf16_t* xpb   = Wob   + (size_t)NLAYERS * D_MODEL * D_INNER;   // 4*64*1024
    bf16_t* dtwb  = xpb   + (size_t)NLAYERS * 64 * D_INNER;        // 4*1024*32

    // one-time weight prep
    cast_bf16_kernel<<<2048, 256, 0, stream>>>(in_proj_w, Wib, (size_t)NLAYERS * 2 * D_INNER * D_MODEL);
    cast_bf16_kernel<<<2048, 256, 0, stream>>>(out_proj_w, Wob, (size_t)NLAYERS * D_MODEL * D_INNER);
    cast_bf16_kernel<<<256, 256, 0, stream>>>(x_proj_w, xpb, (size_t)NLAYERS * 64 * D_INNER);
    cast_bf16_kernel<<<128, 256, 0, stream>>>(dt_proj_w, dtwb, (size_t)NLAYERS * D_INNER * DT_RANK);

    embed_ln_kernel<<<NROWS, 256, 0, stream>>>(src, emb_w, enc_ln_w, enc_ln_b, R);

    for (int L = 0; L < NLAYERS; L++) {
        const float* AlogL = A_log + (size_t)L * D_INNER * D_STATE;

        add_ln_kernel<<<NROWS, 256, 0, stream>>>(
            R, (L == 0) ? nullptr : H, ln_w + L * D_MODEL, ln_b + L * D_MODEL,
            nullptr, Hb);

        // in_proj -> Xrawb (x half, bf16), Zbufb (z half, bf16)
        gemm_bf16_nt<3><<<dim3(16, 64), 256, 0, stream>>>(
            Hb, Wib + (size_t)L * 2 * D_INNER * D_MODEL, nullptr, 0, D_MODEL,
            nullptr, nullptr, nullptr, Xrawb, Zbufb);

        conv_silu_kernel<<<(NROWS * D_INNER) / 256, 256, 0, stream>>>(
            Xrawb, conv_w + (size_t)L * D_INNER * D_CONV, conv_b + (size_t)L * D_INNER, XCb);

        // x_proj: dt lowrank (bf16) + B/C bf16-packed pair-interleaved
        gemm_xp_bf16<<<NROWS / 64, 128, 0, stream>>>(
            XCb, xpb + (size_t)L * 64 * D_INNER, XDlow, BCb, D_INNER);

        // dt_proj (K=32) + softplus + pack {dt, dt*x} -> DTXb
        gemm_bf16_nt<2><<<dim3(8, 64), 256, 0, stream>>>(
            XDlow, dtwb + (size_t)L * D_INNER * DT_RANK, nullptr, 0, DT_RANK,
            dt_proj_b + (size_t)L * D_INNER, (const unsigned short*)XCb, DTXb,
            nullptr, nullptr);

        // chunked scan: summaries -> propagate -> recompute+combine
        scan_pA_kernel<<<dim3(B_SZ * 64, NCHUNK), 256, 0, stream>>>(
            DTXb, BCb, AlogL, DcB, UcB);
        scan_p2_kernel<<<256, 256, 0, stream>>>(AlogL, DcB, UcB, HcB);
        scan_pB_kernel<<<dim3(B_SZ * 64, NCHUNK), 256, 0, stream>>>(
            DTXb, BCb, HcB, AlogL, Zbufb, D_skip + (size_t)L * D_INNER, XCb);

        // out_proj
        gemm_bf16_nt<0><<<dim3(4, 64), 256, 0, stream>>>(
            XCb, Wob + (size_t)L * D_MODEL * D_INNER, H, D_MODEL, D_INNER,
            nullptr, nullptr, nullptr, nullptr, nullptr);
    }

    add_ln_kernel<<<NROWS, 256, 0, stream>>>(R, H, normf_w, normf_b, out, nullptr);
}